// Round 18
// baseline (1712.943 us; speedup 1.0000x reference)
//
#include <hip/hip_runtime.h>
#include <hip/hip_bf16.h>
#include <math.h>

#define S 2304
#define HDIM 1152
#define NHEAD 16
#define HD 72
#define INTER 4304
#define INTERP 4352   // INTER padded to multiple of 128
#define DEPTH 4
#define MERGED 4608
#define OUTD 2048
#define KIN 1536
#define NSPLIT 4
#define KHALF (S / NSPLIT)   // 576

typedef float f4 __attribute__((ext_vector_type(4)));
typedef short s8v __attribute__((ext_vector_type(8)));

// ---------- helpers ----------
__device__ __forceinline__ int pos_id_of(int s) {
  int a = s / 96;
  int r = s % 96;
  int b = r >> 2;
  int c = (r >> 1) & 1;
  int d = r & 1;
  return a * 96 + c * 48 + b * 2 + d;
}

__device__ __forceinline__ float gelu_f(float v) {
  const float c = 0.7978845608028654f;
  float t = tanhf(c * (v + 0.044715f * v * v * v));
  return 0.5f * v * (1.f + t);
}

__device__ __forceinline__ unsigned short f2b(float f) {
  __hip_bfloat16 h = __float2bfloat16(f);
  unsigned short u;
  __builtin_memcpy(&u, &h, 2);
  return u;
}
__device__ __forceinline__ float b2f(unsigned short u) {
  return __uint_as_float(((unsigned int)u) << 16);
}

__device__ __forceinline__ void gload16(const void* g, void* l) {
  __builtin_amdgcn_global_load_lds(
      (const __attribute__((address_space(1))) void*)g,
      (__attribute__((address_space(3))) void*)l, 16, 0, 0);
}

// bijective XCD-chunk swizzle (m204 form)
__device__ __forceinline__ int xcd_swz(int flat, int nwg) {
  int q = nwg >> 3, r8 = nwg & 7;
  int xcd = flat & 7, lin = flat >> 3;
  return (xcd < r8 ? xcd * (q + 1) : r8 * (q + 1) + (xcd - r8) * q) + lin;
}

// ---------- fp32 -> bf16 convert (single region, with K padding) ----------
__global__ void __launch_bounds__(256) cvt_kernel(
    const float* __restrict__ src, unsigned short* __restrict__ dst,
    int N, int Ksrc, int Kdst)
{
  int idx = blockIdx.x * 256 + threadIdx.x;
  int kc = Kdst >> 3;
  if (idx >= N * kc) return;
  int r = idx / kc;
  int c8 = (idx % kc) << 3;
  const float* sp = src + (size_t)r * Ksrc + c8;
  unsigned short outv[8];
#pragma unroll
  for (int e = 0; e < 8; ++e)
    outv[e] = (c8 + e < Ksrc) ? f2b(sp[e]) : (unsigned short)0;
  *(uint4*)(dst + (size_t)r * Kdst + c8) = *(uint4*)outv;
}

// ---------- fused 4-region fp32 -> bf16 convert ----------
__global__ void __launch_bounds__(256) cvt4_kernel(
    const float* __restrict__ s0, unsigned short* __restrict__ d0, int Ks0, int Kd0, int e0,
    const float* __restrict__ s1, unsigned short* __restrict__ d1, int Ks1, int Kd1, int e1,
    const float* __restrict__ s2, unsigned short* __restrict__ d2, int Ks2, int Kd2, int e2,
    const float* __restrict__ s3, unsigned short* __restrict__ d3, int Ks3, int Kd3, int e3)
{
  int idx = blockIdx.x * 256 + threadIdx.x;
  const float* src; unsigned short* dst; int Ksrc, Kdst, rel;
  if (idx < e0)      { src = s0; dst = d0; Ksrc = Ks0; Kdst = Kd0; rel = idx; }
  else if (idx < e1) { src = s1; dst = d1; Ksrc = Ks1; Kdst = Kd1; rel = idx - e0; }
  else if (idx < e2) { src = s2; dst = d2; Ksrc = Ks2; Kdst = Kd2; rel = idx - e1; }
  else if (idx < e3) { src = s3; dst = d3; Ksrc = Ks3; Kdst = Kd3; rel = idx - e2; }
  else return;
  int kc = Kdst >> 3;
  int r = rel / kc;
  int c8 = (rel % kc) << 3;
  const float* sp = src + (size_t)r * Ksrc + c8;
  unsigned short outv[8];
#pragma unroll
  for (int e = 0; e < 8; ++e)
    outv[e] = (c8 + e < Ksrc) ? f2b(sp[e]) : (unsigned short)0;
  *(uint4*)(dst + (size_t)r * Kdst + c8) = *(uint4*)outv;
}

// ---------- bf16 MFMA NT GEMM, 64x128 tile ----------
__global__ void __launch_bounds__(256) gemm_bf16_m64_kernel(
    const unsigned short* __restrict__ A, const unsigned short* __restrict__ B,
    const float* __restrict__ bias, void* __restrict__ Cout,
    int M, int Nreal, int K, int lda, int ldb, int ldc, int act, int outbf)
{
  __shared__ unsigned short Asm[2][64 * 32];
  __shared__ unsigned short Bsm[2][128 * 32];
  const int tid = threadIdx.x;
  const int lane = tid & 63;
  const int wv = tid >> 6;

  int flat = blockIdx.y * gridDim.x + blockIdx.x;
  int swz = xcd_swz(flat, gridDim.x * gridDim.y);
  const int bm = (swz / gridDim.x) * 64;
  const int bn = (swz % gridDim.x) * 128;

  const int g8 = (lane >> 4) << 3;
  const int lr = lane & 15;

  const int lrow = lane >> 2;
  const int kq = (lane & 3) << 3;
  const unsigned short* AgP = A + (size_t)(bm + wv * 16 + lrow) * lda + kq;
  int brow1 = bn + wv * 16 + lrow;      if (brow1 >= Nreal) brow1 = Nreal - 1;
  int brow2 = bn + 64 + wv * 16 + lrow; if (brow2 >= Nreal) brow2 = Nreal - 1;
  const unsigned short* BgP1 = B + (size_t)brow1 * ldb + kq;
  const unsigned short* BgP2 = B + (size_t)brow2 * ldb + kq;

  f4 acc[4][2];
#pragma unroll
  for (int m = 0; m < 4; ++m)
#pragma unroll
    for (int n = 0; n < 2; ++n) { acc[m][n].x = 0.f; acc[m][n].y = 0.f; acc[m][n].z = 0.f; acc[m][n].w = 0.f; }

  const int nt = K >> 5;
  gload16(AgP, &Asm[0][(wv * 16) * 32]);
  gload16(BgP1, &Bsm[0][(wv * 16) * 32]);
  gload16(BgP2, &Bsm[0][(64 + wv * 16) * 32]);
  asm volatile("s_waitcnt vmcnt(0)" ::: "memory");
  __syncthreads();

  int cur = 0;
  for (int t = 0; t < nt; ++t) {
    if (t + 1 < nt) {
      int ko = (t + 1) << 5;
      gload16(AgP + ko, &Asm[cur ^ 1][(wv * 16) * 32]);
      gload16(BgP1 + ko, &Bsm[cur ^ 1][(wv * 16) * 32]);
      gload16(BgP2 + ko, &Bsm[cur ^ 1][(64 + wv * 16) * 32]);
    }
    s8v af[4], bf[2];
#pragma unroll
    for (int m = 0; m < 4; ++m)
      af[m] = *(const s8v*)&Asm[cur][(m * 16 + lr) * 32 + g8];
#pragma unroll
    for (int n = 0; n < 2; ++n)
      bf[n] = *(const s8v*)&Bsm[cur][(wv * 32 + n * 16 + lr) * 32 + g8];
#pragma unroll
    for (int m = 0; m < 4; ++m)
#pragma unroll
      for (int n = 0; n < 2; ++n)
        acc[m][n] = __builtin_amdgcn_mfma_f32_16x16x32_bf16(af[m], bf[n], acc[m][n], 0, 0, 0);
    asm volatile("s_waitcnt vmcnt(0)" ::: "memory");
    __syncthreads();
    cur ^= 1;
  }

  const int g4 = (lane >> 4) << 2;
#pragma unroll
  for (int m = 0; m < 4; ++m) {
    int r = bm + m * 16 + g4;
#pragma unroll
    for (int n = 0; n < 2; ++n) {
      int cidx = bn + wv * 32 + n * 16 + lr;
      float bb = (cidx < Nreal) ? bias[cidx] : 0.f;
#pragma unroll
      for (int j = 0; j < 4; ++j) {
        int rr = r + j;
        float v = acc[m][n][j] + bb;
        if (act) v = gelu_f(v);
        if (cidx >= Nreal) v = 0.f;
        if (outbf) ((unsigned short*)Cout)[(size_t)rr * ldc + cidx] = f2b(v);
        else       ((float*)Cout)[(size_t)rr * ldc + cidx] = v;
      }
    }
  }
}

// ---------- split-K variant: blockIdx.z = K-chunk, writes fp32 partials ----------
__global__ void __launch_bounds__(256) gemm_bf16_splitk_kernel(
    const unsigned short* __restrict__ A, const unsigned short* __restrict__ B,
    float* __restrict__ Cpart, float* __restrict__ Calt, float* __restrict__ Calt2,
    int M, int N, int Kc, int lda, int ldb)
{
  __shared__ unsigned short Asm[2][128 * 32];
  __shared__ unsigned short Bsm[2][128 * 32];
  const int tid = threadIdx.x;
  const int lane = tid & 63;
  const int wv = tid >> 6;
  const int wr = wv >> 1, wc = wv & 1;

  int flat = blockIdx.y * gridDim.x + blockIdx.x;
  int swz = xcd_swz(flat, gridDim.x * gridDim.y);
  const int bm = (swz / gridDim.x) * 128;
  const int bn = (swz % gridDim.x) * 128;
  const int z = blockIdx.z;
  const int kbase = z * Kc;

  const int g8 = (lane >> 4) << 3;
  const int lr = lane & 15;

  const int srow = wv * 32 + (lane >> 2);
  const int kcol = (lane & 3) << 3;
  int ar0 = bm + srow;      if (ar0 >= M) ar0 = M - 1;
  int ar1 = bm + srow + 16; if (ar1 >= M) ar1 = M - 1;
  int br0 = bn + srow;      if (br0 >= N) br0 = N - 1;
  int br1 = bn + srow + 16; if (br1 >= N) br1 = N - 1;
  const unsigned short* Ag0 = A + (size_t)ar0 * lda + kbase + kcol;
  const unsigned short* Ag1 = A + (size_t)ar1 * lda + kbase + kcol;
  const unsigned short* Bg0 = B + (size_t)br0 * ldb + kbase + kcol;
  const unsigned short* Bg1 = B + (size_t)br1 * ldb + kbase + kcol;

  f4 acc[4][4];
#pragma unroll
  for (int m = 0; m < 4; ++m)
#pragma unroll
    for (int n = 0; n < 4; ++n) { acc[m][n].x = 0.f; acc[m][n].y = 0.f; acc[m][n].z = 0.f; acc[m][n].w = 0.f; }

  const int nt = Kc >> 5;
  gload16(Ag0, &Asm[0][(wv * 32) * 32]);
  gload16(Ag1, &Asm[0][(wv * 32 + 16) * 32]);
  gload16(Bg0, &Bsm[0][(wv * 32) * 32]);
  gload16(Bg1, &Bsm[0][(wv * 32 + 16) * 32]);
  asm volatile("s_waitcnt vmcnt(0)" ::: "memory");
  __syncthreads();

  int cur = 0;
  for (int t = 0; t < nt; ++t) {
    if (t + 1 < nt) {
      int ko = (t + 1) << 5;
      gload16(Ag0 + ko, &Asm[cur ^ 1][(wv * 32) * 32]);
      gload16(Ag1 + ko, &Asm[cur ^ 1][(wv * 32 + 16) * 32]);
      gload16(Bg0 + ko, &Bsm[cur ^ 1][(wv * 32) * 32]);
      gload16(Bg1 + ko, &Bsm[cur ^ 1][(wv * 32 + 16) * 32]);
    }
    s8v af[4], bf[4];
#pragma unroll
    for (int m = 0; m < 4; ++m)
      af[m] = *(const s8v*)&Asm[cur][(wr * 64 + m * 16 + lr) * 32 + g8];
#pragma unroll
    for (int n = 0; n < 4; ++n)
      bf[n] = *(const s8v*)&Bsm[cur][(wc * 64 + n * 16 + lr) * 32 + g8];
#pragma unroll
    for (int m = 0; m < 4; ++m)
#pragma unroll
      for (int n = 0; n < 4; ++n)
        acc[m][n] = __builtin_amdgcn_mfma_f32_16x16x32_bf16(af[m], bf[n], acc[m][n], 0, 0, 0);
    asm volatile("s_waitcnt vmcnt(0)" ::: "memory");
    __syncthreads();
    cur ^= 1;
  }

  float* Cz = (Calt && z == 1) ? Calt
            : ((Calt2 && z == 2) ? Calt2 : (Cpart + (size_t)z * M * N));
  const int g4 = (lane >> 4) << 2;
#pragma unroll
  for (int m = 0; m < 4; ++m) {
    int r = bm + wr * 64 + m * 16 + g4;
#pragma unroll
    for (int n = 0; n < 4; ++n) {
      int cidx = bn + wc * 64 + n * 16 + lr;
      if (cidx < N) {
#pragma unroll
        for (int j = 0; j < 4; ++j) {
          int rr = r + j;
          if (rr < M) Cz[(size_t)rr * N + cidx] = acc[m][n][j];
        }
      }
    }
  }
}

// ---------- combine split-K partials (generic, fp32 out; used by merger fc2) ----------
__global__ void __launch_bounds__(256) combine_gemm_kernel(
    const float* __restrict__ Cpart, int nz, const float* __restrict__ bias,
    const float* __restrict__ resid, float* __restrict__ out, int M, int N)
{
  int idx = blockIdx.x * 256 + threadIdx.x;
  int total = (M * N) >> 2;
  if (idx >= total) return;
  int r = idx / (N >> 2);
  int c4 = (idx % (N >> 2)) << 2;
  size_t off = (size_t)r * N + c4;
  float4 s = *(const float4*)(Cpart + off);
  for (int z = 1; z < nz; ++z) {
    float4 p = *(const float4*)(Cpart + (size_t)z * M * N + off);
    s.x += p.x; s.y += p.y; s.z += p.z; s.w += p.w;
  }
  float4 b = *(const float4*)(bias + c4);
  s.x += b.x; s.y += b.y; s.z += b.z; s.w += b.w;
  if (resid) {
    float4 rv = *(const float4*)(resid + off);
    s.x += rv.x; s.y += rv.y; s.z += rv.z; s.w += rv.w;
  }
  *(float4*)(out + off) = s;
}

// ---------- combine 2-3 split-K partials + bias + gelu -> bf16 (merger fc1) ----------
__global__ void __launch_bounds__(256) combine_gelu_kernel(
    const float* __restrict__ p0, const float* __restrict__ p1,
    const float* __restrict__ p2, const float* __restrict__ bias,
    unsigned short* __restrict__ out, int M, int N)
{
  int idx = blockIdx.x * 256 + threadIdx.x;
  int total = (M * N) >> 2;
  if (idx >= total) return;
  int r = idx / (N >> 2);
  int c4 = (idx % (N >> 2)) << 2;
  size_t off = (size_t)r * N + c4;
  float4 a = *(const float4*)(p0 + off);
  float4 b = *(const float4*)(p1 + off);
  float4 bi = *(const float4*)(bias + c4);
  float sx = a.x + b.x + bi.x, sy = a.y + b.y + bi.y;
  float sz = a.z + b.z + bi.z, sw = a.w + b.w + bi.w;
  if (p2) {
    float4 cc = *(const float4*)(p2 + off);
    sx += cc.x; sy += cc.y; sz += cc.z; sw += cc.w;
  }
  unsigned short o[4];
  o[0] = f2b(gelu_f(sx));
  o[1] = f2b(gelu_f(sy));
  o[2] = f2b(gelu_f(sz));
  o[3] = f2b(gelu_f(sw));
  *(uint2*)(out + off) = *(uint2*)o;
}

// ---------- fused split-K combine (+bias, +resid, +pos) + LayerNorm ----------
__global__ void __launch_bounds__(256) combine_ln_kernel(
    const float* __restrict__ Cpart, int nz, const float* __restrict__ bias,
    const float* __restrict__ resid, const float* __restrict__ pos_tab,
    float* __restrict__ xout, const float* __restrict__ lnw,
    const float* __restrict__ lnb, unsigned short* __restrict__ hout)
{
  __shared__ float red[8];
  const int row = blockIdx.x;
  const int tid = threadIdx.x;
  const float* pos = pos_tab ? pos_tab + (size_t)pos_id_of(row) * HDIM : nullptr;
  float v[5];
  float s1 = 0.f;
#pragma unroll
  for (int t = 0; t < 5; ++t) {
    int i = tid + t * 256;
    float s = 0.f;
    if (i < HDIM) {
      size_t off = (size_t)row * HDIM + i;
      s = Cpart[off];
      for (int z = 1; z < nz; ++z) s += Cpart[(size_t)z * ((size_t)S * HDIM) + off];
      s += bias[i];
      if (resid) s += resid[off];
      if (pos) s += pos[i];
      xout[off] = s;
    }
    v[t] = s;
    s1 += s;
  }
#pragma unroll
  for (int off = 32; off > 0; off >>= 1) s1 += __shfl_down(s1, off);
  if ((tid & 63) == 0) red[tid >> 6] = s1;
  __syncthreads();
  float mean = (red[0] + red[1] + red[2] + red[3]) * (1.f / HDIM);
  float s2 = 0.f;
#pragma unroll
  for (int t = 0; t < 5; ++t) {
    int i = tid + t * 256;
    if (i < HDIM) { float d = v[t] - mean; s2 += d * d; }
  }
#pragma unroll
  for (int off = 32; off > 0; off >>= 1) s2 += __shfl_down(s2, off);
  __syncthreads();
  if ((tid & 63) == 0) red[tid >> 6] = s2;
  __syncthreads();
  float var = (red[0] + red[1] + red[2] + red[3]) * (1.f / HDIM);
  float rstd = rsqrtf(var + 1e-6f);
#pragma unroll
  for (int t = 0; t < 5; ++t) {
    int i = tid + t * 256;
    if (i < HDIM)
      hout[(size_t)row * HDIM + i] = f2b(lnw[i] * ((v[t] - mean) * rstd) + lnb[i]);
  }
}

// ---------- RoPE tables ----------
__global__ void rope_tables_kernel(float* __restrict__ cosT, float* __restrict__ sinT)
{
  int s = blockIdx.x;
  int j = threadIdx.x;
  if (j >= 36) return;
  int pid = pos_id_of(s);
  float hp = (float)(pid / 48);
  float wp = (float)(pid % 48);
  int f = (j < 18) ? j : (j - 18);
  float inv = powf(10000.f, -(2.f * (float)f) / 36.f);
  float ang = ((j < 18) ? hp : wp) * inv;
  cosT[s * 36 + j] = cosf(ang);
  sinT[s * 36 + j] = sinf(ang);
}

// ---------- seg ids ----------
__global__ void seg_kernel(const int* __restrict__ cu, int n_cu, int* __restrict__ seg)
{
  int i = blockIdx.x * 256 + threadIdx.x;
  if (i >= S) return;
  int s = 0;
  for (int t = 0; t < n_cu; ++t) s += (cu[t] <= i) ? 1 : 0;
  seg[i] = s;
}

// ---------- RoPE apply (bf16 in/out, fp32 math) ----------
__global__ void __launch_bounds__(256) rope_kernel(unsigned short* __restrict__ qkv,
    const float* __restrict__ cosT, const float* __restrict__ sinT)
{
  int idx = blockIdx.x * 256 + threadIdx.x;
  int d = idx % 36; int t = idx / 36;
  int hh = t % NHEAD; t /= NHEAD;
  int qk = t & 1; int s = t >> 1;
  unsigned short* base = qkv + (size_t)s * 3456 + qk * 1152 + hh * 72;
  float c = cosT[s * 36 + d], sn = sinT[s * 36 + d];
  float x0 = b2f(base[d]), x1 = b2f(base[d + 36]);
  base[d] = f2b(x0 * c - x1 * sn);
  base[d + 36] = f2b(x1 * c + x0 * sn);
}

// ---------- MFMA flash attention: fused QK, stride-72 LDS (2-way banks, 30KB) ----------
#define KT 64
#define LSTR 72   // LDS row stride in shorts: 144B = 36 banks -> 2-way conflicts only
#define ASCALE2 (0.11785113019775793f * 1.4426950408889634f)
#define DEFER_THR 11.5415603f   // 8 * log2(e)

__global__ void __launch_bounds__(256) flash_mfma_kernel(
    const unsigned short* __restrict__ qkv, unsigned short* __restrict__ opart,
    float* __restrict__ ml, const int* __restrict__ seg)
{
  __shared__ __align__(16) unsigned short Ks[64 * LSTR];
  __shared__ __align__(16) unsigned short Vt[80 * LSTR];
  __shared__ __align__(16) unsigned short Ps[4][16 * LSTR];

  const int tid = threadIdx.x;
  const int lane = tid & 63;
  const int wv = tid >> 6;
  const int g = lane >> 4;
  const int c = lane & 15;
  const int cm = c & 7;

  int flat = (blockIdx.z * NHEAD + blockIdx.y) * (S / 128) + blockIdx.x;
  int swz = xcd_swz(flat, (S / 128) * NHEAD * NSPLIT);
  const int q0 = (swz % (S / 128)) * 128;
  const int hh = (swz / (S / 128)) % NHEAD;
  const int sidx = swz / ((S / 128) * NHEAD);
  const int kbeg = sidx * KHALF;
  const int qr = q0 + wv * 32;

  // zero Vt pad rows 72..79 (72 cols * 8 rows = 288 uints)
  for (int i = tid; i < 288; i += 256)
    ((unsigned int*)&Vt[72 * LSTR])[i] = 0u;

  const bool uni = (seg[q0] == seg[q0 + 127]) && (seg[kbeg] == seg[kbeg + KHALF - 1])
                && (seg[q0] == seg[kbeg]);
  const int msgA = seg[qr + c];
  const int msgB = seg[qr + 16 + c];

  s8v qfA[3], qfB[3];
  {
    const unsigned short* qa = qkv + (size_t)(qr + c) * 3456 + hh * HD;
    const unsigned short* qb = qkv + (size_t)(qr + 16 + c) * 3456 + hh * HD;
#pragma unroll
    for (int ks = 0; ks < 3; ++ks) {
      int k = ks * 32 + g * 8;
      if (k <= 64) { qfA[ks] = *(const s8v*)(qa + k); qfB[ks] = *(const s8v*)(qb + k); }
      else {
        s8v z;
#pragma unroll
        for (int t = 0; t < 8; ++t) z[t] = 0;
        qfA[ks] = z; qfB[ks] = z;
      }
    }
  }

  float mA = -1e30f, lA = 0.f, mB = -1e30f, lB = 0.f;
  f4 accoA[5], accoB[5];
#pragma unroll
  for (int n = 0; n < 5; ++n) {
    accoA[n].x = 0.f; accoA[n].y = 0.f; accoA[n].z = 0.f; accoA[n].w = 0.f;
    accoB[n].x = 0.f; accoB[n].y = 0.f; accoB[n].z = 0.f; accoB[n].w = 0.f;
  }

  uint4 kreg[3], vreg[3];

#define STAGE_LOAD(KT0)                                                                  \
  {                                                                                      \
    _Pragma("unroll")                                                                    \
    for (int ii = 0; ii < 3; ++ii) {                                                     \
      int idx = tid + ii * 256;                                                          \
      if (idx < 576) {                                                                   \
        int rK = idx / 9, cK = idx % 9;                                                  \
        kreg[ii] = *(const uint4*)(qkv + (size_t)((KT0) + rK) * 3456 + 1152 + hh * HD + cK * 8); \
        int rV = idx & 63, cV = idx >> 6;                                                \
        vreg[ii] = *(const uint4*)(qkv + (size_t)((KT0) + rV) * 3456 + 2304 + hh * HD + cV * 8); \
      }                                                                                  \
    }                                                                                    \
  }

#define STAGE_WRITE()                                                                    \
  {                                                                                      \
    _Pragma("unroll")                                                                    \
    for (int ii = 0; ii < 3; ++ii) {                                                     \
      int idx = tid + ii * 256;                                                          \
      if (idx < 576) {                                                                   \
        int rK = idx / 9, cK = idx % 9;                                                  \
        int colx = (cK < 8) ? ((cK ^ (rK & 7)) << 3) : 64;                               \
        *(uint4*)&Ks[rK * LSTR + colx] = kreg[ii];                                       \
        int rV = idx & 63, cV = idx >> 6;                                                \
        unsigned short vv[8];                                                            \
        *(uint4*)vv = vreg[ii];                                                          \
        _Pragma("unroll")                                                                \
        for (int e = 0; e < 8; ++e) {                                                    \
          int drow = cV * 8 + e;                                                         \
          Vt[drow * LSTR + (rV ^ ((drow & 7) << 3))] = vv[e];                            \
        }                                                                                \
      }                                                                                  \
    }                                                                                    \
  }

// softmax + Ps write + O-rescale + PV for one sub-block (scores in ACCS; Ps[wv] reused
// across sub-blocks -- safe via same-wave in-order DS execution)
#define SOFTMAX_PV(ACCS, MSG, MM, LL, ACCO)                                              \
  {                                                                                      \
    float sc[4][4];                                                                      \
    float mx = -1e30f;                                                                   \
    if (uni) {                                                                           \
      _Pragma("unroll")                                                                  \
      for (int nk = 0; nk < 4; ++nk)                                                     \
        _Pragma("unroll")                                                                \
        for (int j = 0; j < 4; ++j) {                                                    \
          float vv = ACCS[nk][j] * ASCALE2;                                              \
          sc[nk][j] = vv; mx = fmaxf(mx, vv);                                            \
        }                                                                                \
    } else {                                                                             \
      _Pragma("unroll")                                                                  \
      for (int nk = 0; nk < 4; ++nk)                                                     \
        _Pragma("unroll")                                                                \
        for (int j = 0; j < 4; ++j) {                                                    \
          int kk = k0 + nk * 16 + g * 4 + j;                                             \
          float vv = ACCS[nk][j] * ASCALE2 + ((seg[kk] == MSG) ? 0.f : -1e9f);            \
          sc[nk][j] = vv; mx = fmaxf(mx, vv);                                            \
        }                                                                                \
    }                                                                                    \
    mx = fmaxf(mx, __shfl_xor(mx, 16));                                                  \
    mx = fmaxf(mx, __shfl_xor(mx, 32));                                                  \
    const bool allkeep = __all(mx <= MM + DEFER_THR);                                    \
    float al = 1.0f;                                                                     \
    if (!allkeep) {                                                                      \
      float mn = fmaxf(MM, mx);                                                          \
      al = exp2f(MM - mn);                                                               \
      MM = mn;                                                                           \
    }                                                                                    \
    float rsum = 0.f;                                                                    \
    float p[4][4];                                                                       \
    _Pragma("unroll")                                                                    \
    for (int nk = 0; nk < 4; ++nk)                                                       \
      _Pragma("unroll")                                                                  \
      for (int j = 0; j < 4; ++j) {                                                      \
        float pv = exp2f(sc[nk][j] - MM);                                                \
        p[nk][j] = pv; rsum += pv;                                                       \
      }                                                                                  \
    rsum += __shfl_xor(rsum, 16);                                                        \
    rsum += __shfl_xor(rsum, 32);                                                        \
    LL = LL * al + rsum;                                                                 \
    _Pragma("unroll")                                                                    \
    for (int nk = 0; nk < 4; ++nk) {                                                     \
      unsigned int w0 = (unsigned int)f2b(p[nk][0]) | ((unsigned int)f2b(p[nk][1]) << 16); \
      unsigned int w1 = (unsigned int)f2b(p[nk][2]) | ((unsigned int)f2b(p[nk][3]) << 16); \
      uint2 wv2; wv2.x = w0; wv2.y = w1;                                                 \
      *(uint2*)&Ps[wv][c * LSTR + ((nk * 16 + g * 4) ^ (cm << 3))] = wv2;                \
    }                                                                                    \
    if (!allkeep) {                                                                      \
      float alpha_row[4];                                                                \
      _Pragma("unroll")                                                                  \
      for (int j = 0; j < 4; ++j)                                                        \
        alpha_row[j] = __shfl(al, (lane & 48) | (g * 4 + j));                            \
      _Pragma("unroll")                                                                  \
      for (int n = 0; n < 5; ++n)                                                        \
        _Pragma("unroll")                                                                \
        for (int j = 0; j < 4; ++j) ACCO[n][j] *= alpha_row[j];                          \
    }                                                                                    \
    asm volatile("s_waitcnt lgkmcnt(0)" ::: "memory");                                   \
    __builtin_amdgcn_sched_barrier(0);                                                   \
    _Pragma("unroll")                                                                    \
    for (int ks = 0; ks < 2; ++ks) {                                                     \
      const int poff = ((ks * 4 + g) ^ cm) << 3;                                         \
      s8v pa = *(const s8v*)&Ps[wv][c * LSTR + poff];                                    \
      _Pragma("unroll")                                                                  \
      for (int n = 0; n < 5; ++n) {                                                      \
        s8v vb = *(const s8v*)&Vt[(n * 16 + c) * LSTR + poff];                           \
        ACCO[n] = __builtin_amdgcn_mfma_f32_16x16x32_bf16(pa, vb, ACCO[n], 0, 0, 0);     \
      }                                                                                  \
    }                                                                                    \
  }

  STAGE_LOAD(kbeg);
  asm volatile("s_waitcnt vmcnt(0)" ::: "memory");
  STAGE_WRITE();
  asm volatile("s_waitcnt lgkmcnt(0)" ::: "memory");
  __builtin_amdgcn_s_barrier();
  __builtin_amdgcn_sched_barrier(0);

  for (int k0 = kbeg; k0 < kbeg + KHALF; k0 += KT) {
    const bool more = (k0 + KT < kbeg + KHALF);
    if (more) STAGE_LOAD(k0 + KT);

    // fused QK^T: each Ks read feeds both sub-blocks' MFMAs
    f4 accsA[4], accsB[4];
#pragma unroll
    for (int nk = 0; nk < 4; ++nk) {
      accsA[nk].x = 0.f; accsA[nk].y = 0.f; accsA[nk].z = 0.f; accsA[nk].w = 0.f;
      accsB[nk].x = 0.f; accsB[nk].y = 0.f; accsB[nk].z = 0.f; accsB[nk].w = 0.f;
    }
#pragma unroll
    for (int ks = 0; ks < 3; ++ks) {
      const int koff = (ks < 2) ? (((ks * 4 + g) ^ cm) << 3) : 64;
#pragma unroll
      for (int nk = 0; nk < 4; ++nk) {
        s8v bk = *(const s8v*)&Ks[(nk * 16 + c) * LSTR + koff];
        accsA[nk] = __builtin_amdgcn_mfma_f32_16x16x32_bf16(bk, qfA[ks], accsA[nk], 0, 0, 0);
        accsB[nk] = __builtin_amdgcn_mfma_f32_16x16x32_bf16(bk, qfB[ks], accsB[nk], 0, 0, 0);
      }
    }

    SOFTMAX_PV(accsA, msgA, mA, lA, accoA);
    SOFTMAX_PV(accsB, msgB, mB, lB, accoB);

    asm volatile("s_waitcnt lgkmcnt(0)" ::: "memory");
    __builtin_amdgcn_s_barrier();
    if (more) {
      asm volatile("s_waitcnt vmcnt(0)" ::: "memory");
      STAGE_WRITE();
      asm volatile("s_waitcnt lgkmcnt(0)" ::: "memory");
    }
    __builtin_amdgcn_s_barrier();
    __builtin_amdgcn_sched_barrier(0);
  }

  unsigned short* op = opart + (size_t)(sidx * NHEAD + hh) * S * 72;
  float lrA[4], mrA[4], lrB[4], mrB[4];
#pragma unroll
  for (int j = 0; j < 4; ++j) {
    int src = (lane & 48) | (g * 4 + j);
    lrA[j] = __shfl(lA, src); mrA[j] = __shfl(mA, src);
    lrB[j] = __shfl(lB, src); mrB[j] = __shfl(mB, src);
  }
#pragma unroll
  for (int n = 0; n < 5; ++n) {
    int col = n * 16 + c;
    if (col < HD) {
#pragma unroll
      for (int j = 0; j < 4; ++j) {
        int rowA = qr + g * 4 + j;
        op[(size_t)rowA * 72 + col] = f2b(accoA[n][j]);
        op[(size_t)(rowA + 16) * 72 + col] = f2b(accoB[n][j]);
      }
    }
  }
  if (c == 0) {
#pragma unroll
    for (int j = 0; j < 4; ++j) {
      int rowA = qr + g * 4 + j;
      float2 va; va.x = mrA[j]; va.y = lrA[j];
      *(float2*)&ml[((size_t)(sidx * NHEAD + hh) * S + rowA) * 2] = va;
      float2 vb; vb.x = mrB[j]; vb.y = lrB[j];
      *(float2*)&ml[((size_t)(sidx * NHEAD + hh) * S + rowA + 16) * 2] = vb;
    }
  }
}

// ---------- combine the NSPLIT attention partials (exp2 domain) ----------
__global__ void __launch_bounds__(256) attn_combine_kernel(
    const unsigned short* __restrict__ opart, const float* __restrict__ ml,
    unsigned short* __restrict__ oout)
{
  int idx = blockIdx.x * 256 + threadIdx.x;
  int d = idx % 72;
  int row = (idx / 72) % S;
  int hh = idx / (72 * S);
  float mv[NSPLIT], lv[NSPLIT];
  float ms = -1e30f;
#pragma unroll
  for (int z = 0; z < NSPLIT; ++z) {
    size_t b = (size_t)(z * NHEAD + hh) * S + row;
    mv[z] = ml[b * 2]; lv[z] = ml[b * 2 + 1];
    ms = fmaxf(ms, mv[z]);
  }
  float l = 0.f, o = 0.f;
#pragma unroll
  for (int z = 0; z < NSPLIT; ++z) {
    size_t b = (size_t)(z * NHEAD + hh) * S + row;
    float a = exp2f(mv[z] - ms);
    l += a * lv[z];
    o += a * b2f(opart[b * 72 + d]);
  }
  oout[(size_t)row * HDIM + hh * 72 + d] = f2b(o / l);
}

// ---------- launch ----------
extern "C" void kernel_launch(void* const* d_in, const int* in_sizes, int n_in,
                              void* d_out, int out_size, void* d_ws, size_t ws_size,
                              hipStream_t stream)
{
  (void)n_in; (void)out_size; (void)ws_size;
  const float* pix    = (const float*)d_in[0];
  const int*   cu     = (const int*)d_in[1];
  const int    n_cu   = in_sizes[1];
  const float* conv_w = (const float*)d_in[2];
  const float* conv_b = (const float*)d_in[3];
  const float* pos_tab= (const float*)d_in[4];
  const float* ln1_w  = (const float*)d_in[5];
  const float* ln1_b  = (const float*)d_in[6];
  const float* ln2_w  = (const float*)d_in[7];
  const float* ln2_b  = (const float*)d_in[8];
  const float* qkv_w  = (const float*)d_in[9];
  const float* qkv_b  = (const float*)d_in[10];
  const float* proj_w = (const float*)d_in[11];
  const float* proj_b = (const float*)d_in[12];
  const float* fc1_w  = (const float*)d_in[13];
  const float* fc1_b  = (const float*)d_in[14];
  const float* fc2_w  = (const float*)d_in[15];
  const float* fc2_b  = (const float*)d_in[16];
  const float* mn_w   = (const float*)d_in[17];
  const float* mn_b   = (const float*)d_in[18];
  const float* mf1_w  = (const float*)d_in[19];
  const float* mf1_b  = (const float*)d_in[20];
  const float* mf2_w  = (const float*)d_in[21];
  const float* mf2_b  = (const float*)d_in[22];
  float* out = (float*)d_out;

  float*    x      = (float*)d_ws;                                        // S*HDIM f32
  unsigned short* h_bf   = (unsigned short*)(x + (size_t)S * HDIM);       // S*HDIM bf16
  unsigned short* qkv_bf = h_bf + (size_t)S * HDIM;                       // S*3456 bf16
  unsigned short* A_bf   = qkv_bf + (size_t)S * 3456;                     // S*INTERP bf16
  unsigned short* Wbuf   = A_bf + (size_t)S * INTERP;                     // 4608*4608 bf16
  float*    cosT   = (float*)(Wbuf + (size_t)MERGED * MERGED);
  float*    sinT   = cosT + (size_t)S * 36;
  int*      seg    = (int*)(sinT + (size_t)S * 36);
  unsigned short* pix_bf = A_bf;          // alias (patch embed only)
  unsigned short* opart  = A_bf;          // alias (attention; spills 2.3MB into Wq region, dead by then)
  float*    ml     = (float*)(A_bf + (size_t)NSPLIT * NHEAD * S * 72);
  float*    part_h = (float*)h_bf;        // 21.2 MB region (h_bf+qkv_bf)
  float*    part_q = (float*)qkv_bf;      // 35.9 MB region (qkv_bf+A_bf)

  // per-layer weight sub-buffers inside Wbuf
  unsigned short* Wq = Wbuf;
  unsigned short* Wp = Wq + (size_t)3456 * HDIM;
  unsigned short* W1 = Wp + (size_t)HDIM * HDIM;
  unsigned short* W2 = W1 + (size_t)INTER * HDIM;

  auto cvt = [&](const float* src, unsigned short* dst, int N, int Ksrc, int Kdst) {
    int total = N * (Kdst >> 3);
    cvt_kernel<<<(total + 255) / 256, 256, 0, stream>>>(src, dst, N, Ksrc, Kdst);
  };
  auto gemm64 = [&](const unsigned short* A, const unsigned short* B, const float* bias,
                    void* C, int M, int N, int K, int lda, int ldb, int ldc, int act, int outbf) {
    gemm_bf16_m64_kernel<<<dim3((N + 127) / 128, M / 64), 256, 0, stream>>>(
        A, B, bias, C, M, N, K, lda, ldb, ldc, act, outbf);
  };
  auto splitk = [&](const unsigned short* A, const unsigned short* B, float* part,
                    float* alt, float* alt2, int M, int N, int K, int nz, int lda, int ldb) {
    gemm_bf16_splitk_kernel<<<dim3(N / 128, (M + 127) / 128, nz), 256, 0, stream>>>(
        A, B, part, alt, alt2, M, N, K / nz, lda, ldb);
  };
  auto comb_ln = [&](float* part, int nz, const float* bias, const float* resid,
                     const float* pos, const float* lw, const float* lb) {
    combine_ln_kernel<<<S, 256, 0, stream>>>(part, nz, bias, resid, pos, x, lw, lb, h_bf);
  };

  // patch embed: fused cvt (pix + conv_w) -> split-K(2) -> combine(+pos)+ln1
  {
    int e0 = S * (KIN >> 3);
    int e1 = e0 + HDIM * (KIN >> 3);
    cvt4_kernel<<<(e1 + 255) / 256, 256, 0, stream>>>(
        pix, pix_bf, KIN, KIN, e0,
        conv_w, Wbuf, KIN, KIN, e1,
        nullptr, nullptr, 1, 8, e1,
        nullptr, nullptr, 1, 8, e1);
  }
  splitk(pix_bf, Wbuf, part_h, nullptr, nullptr, S, HDIM, KIN, 2, KIN, KIN);
  rope_tables_kernel<<<S, 64, 0, stream>>>(cosT, sinT);
  seg_kernel<<<(S + 255) / 256, 256, 0, stream>>>(cu, n_cu, seg);
  comb_ln(part_h, 2, conv_b, nullptr, pos_tab, ln1_w, ln1_b);

  for (int layer = 0; layer < DEPTH; ++layer) {
    {
      int e0 = 3456 * (HDIM >> 3);
      int e1 = e0 + HDIM * (HDIM >> 3);
      int e2 = e1 + INTER * (HDIM >> 3);
      int e3 = e2 + HDIM * (INTERP >> 3);
      cvt4_kernel<<<(e3 + 255) / 256, 256, 0, stream>>>(
          qkv_w + (size_t)layer * 3456 * HDIM, Wq, HDIM, HDIM, e0,
          proj_w + (size_t)layer * HDIM * HDIM, Wp, HDIM, HDIM, e1,
          fc1_w + (size_t)layer * INTER * HDIM, W1, HDIM, HDIM, e2,
          fc2_w + (size_t)layer * HDIM * INTER, W2, INTER, INTERP, e3);
    }
    gemm64(h_bf, Wq, qkv_b + layer * 3456, qkv_bf, S, 3456, HDIM, HDIM, HDIM, 3456, 0, 1);
    rope_kernel<<<(S * 2 * NHEAD * 36) / 256, 256, 0, stream>>>(qkv_bf, cosT, sinT);
    flash_mfma_kernel<<<dim3(S / 128, NHEAD, NSPLIT), 256, 0, stream>>>(qkv_bf, opart, ml, seg);
    attn_combine_kernel<<<(NHEAD * S * 72) / 256, 256, 0, stream>>>(opart, ml, h_bf);
    splitk(h_bf, Wp, part_q, nullptr, nullptr, S, HDIM, HDIM, 3, HDIM, HDIM);
    comb_ln(part_q, 3, proj_b + layer * HDIM, x, nullptr,
            ln2_w + layer * HDIM, ln2_b + layer * HDIM);
    gemm64(h_bf, W1, fc1_b + layer * INTER, A_bf, S, INTER, HDIM, HDIM, HDIM, INTERP, 1, 1);
    splitk(A_bf, W2, part_h, nullptr, nullptr, S, HDIM, INTERP, 2, INTERP, INTERP);
    if (layer < DEPTH - 1)
      comb_ln(part_h, 2, fc2_b + layer * HDIM, x, nullptr,
              ln1_w + (layer + 1) * HDIM, ln1_b + (layer + 1) * HDIM);
    else
      comb_ln(part_h, 2, fc2_b + layer * HDIM, x, nullptr, mn_w, mn_b);
  }

  // merger: m_norm lives in h_bf (viewed (576, 4608)); x and qkv_bf now dead.
  cvt(mf1_w, Wbuf, MERGED, MERGED, MERGED);
  // fc1 split-K(3): A = h_bf; partials z0 -> x, z1 -> qkv_bf, z2 -> A_bf + 5.3MB
  {
    float* pz0 = x;
    float* pz1 = (float*)qkv_bf;
    float* pz2 = (float*)(A_bf + (size_t)576 * MERGED);
    splitk(h_bf, Wbuf, pz0, pz1, pz2, 576, MERGED, MERGED, 3, MERGED, MERGED);
    combine_gelu_kernel<<<((576 * MERGED / 4) + 255) / 256, 256, 0, stream>>>(
        pz0, pz1, pz2, mf1_b, A_bf, 576, MERGED);
  }
  cvt(mf2_w, Wbuf, OUTD, MERGED, MERGED);
  splitk(A_bf, Wbuf, part_h, nullptr, nullptr, 576, OUTD, MERGED, 4, MERGED, MERGED);
  combine_gemm_kernel<<<((576 * OUTD / 4) + 255) / 256, 256, 0, stream>>>(
      part_h, 4, mf2_b, nullptr, out, 576, OUTD);
}

// Round 19
// 1639.138 us; speedup vs baseline: 1.0450x; 1.0450x over previous
//
#include <hip/hip_runtime.h>
#include <hip/hip_bf16.h>
#include <math.h>

#define S 2304
#define HDIM 1152
#define NHEAD 16
#define HD 72
#define INTER 4304
#define INTERP 4352   // INTER padded to multiple of 128
#define DEPTH 4
#define MERGED 4608
#define OUTD 2048
#define KIN 1536
#define NSPLIT 4
#define KHALF (S / NSPLIT)   // 576

typedef float f4 __attribute__((ext_vector_type(4)));
typedef short s8v __attribute__((ext_vector_type(8)));

// ---------- helpers ----------
__device__ __forceinline__ int pos_id_of(int s) {
  int a = s / 96;
  int r = s % 96;
  int b = r >> 2;
  int c = (r >> 1) & 1;
  int d = r & 1;
  return a * 96 + c * 48 + b * 2 + d;
}

__device__ __forceinline__ float gelu_f(float v) {
  const float c = 0.7978845608028654f;
  float t = tanhf(c * (v + 0.044715f * v * v * v));
  return 0.5f * v * (1.f + t);
}

__device__ __forceinline__ unsigned short f2b(float f) {
  __hip_bfloat16 h = __float2bfloat16(f);
  unsigned short u;
  __builtin_memcpy(&u, &h, 2);
  return u;
}
__device__ __forceinline__ float b2f(unsigned short u) {
  return __uint_as_float(((unsigned int)u) << 16);
}

__device__ __forceinline__ void gload16(const void* g, void* l) {
  __builtin_amdgcn_global_load_lds(
      (const __attribute__((address_space(1))) void*)g,
      (__attribute__((address_space(3))) void*)l, 16, 0, 0);
}

// bijective XCD-chunk swizzle (m204 form)
__device__ __forceinline__ int xcd_swz(int flat, int nwg) {
  int q = nwg >> 3, r8 = nwg & 7;
  int xcd = flat & 7, lin = flat >> 3;
  return (xcd < r8 ? xcd * (q + 1) : r8 * (q + 1) + (xcd - r8) * q) + lin;
}

// ---------- fp32 -> bf16 convert (single region, with K padding) ----------
__global__ void __launch_bounds__(256) cvt_kernel(
    const float* __restrict__ src, unsigned short* __restrict__ dst,
    int N, int Ksrc, int Kdst)
{
  int idx = blockIdx.x * 256 + threadIdx.x;
  int kc = Kdst >> 3;
  if (idx >= N * kc) return;
  int r = idx / kc;
  int c8 = (idx % kc) << 3;
  const float* sp = src + (size_t)r * Ksrc + c8;
  unsigned short outv[8];
#pragma unroll
  for (int e = 0; e < 8; ++e)
    outv[e] = (c8 + e < Ksrc) ? f2b(sp[e]) : (unsigned short)0;
  *(uint4*)(dst + (size_t)r * Kdst + c8) = *(uint4*)outv;
}

// ---------- fused 4-region fp32 -> bf16 convert ----------
__global__ void __launch_bounds__(256) cvt4_kernel(
    const float* __restrict__ s0, unsigned short* __restrict__ d0, int Ks0, int Kd0, int e0,
    const float* __restrict__ s1, unsigned short* __restrict__ d1, int Ks1, int Kd1, int e1,
    const float* __restrict__ s2, unsigned short* __restrict__ d2, int Ks2, int Kd2, int e2,
    const float* __restrict__ s3, unsigned short* __restrict__ d3, int Ks3, int Kd3, int e3)
{
  int idx = blockIdx.x * 256 + threadIdx.x;
  const float* src; unsigned short* dst; int Ksrc, Kdst, rel;
  if (idx < e0)      { src = s0; dst = d0; Ksrc = Ks0; Kdst = Kd0; rel = idx; }
  else if (idx < e1) { src = s1; dst = d1; Ksrc = Ks1; Kdst = Kd1; rel = idx - e0; }
  else if (idx < e2) { src = s2; dst = d2; Ksrc = Ks2; Kdst = Kd2; rel = idx - e1; }
  else if (idx < e3) { src = s3; dst = d3; Ksrc = Ks3; Kdst = Kd3; rel = idx - e2; }
  else return;
  int kc = Kdst >> 3;
  int r = rel / kc;
  int c8 = (rel % kc) << 3;
  const float* sp = src + (size_t)r * Ksrc + c8;
  unsigned short outv[8];
#pragma unroll
  for (int e = 0; e < 8; ++e)
    outv[e] = (c8 + e < Ksrc) ? f2b(sp[e]) : (unsigned short)0;
  *(uint4*)(dst + (size_t)r * Kdst + c8) = *(uint4*)outv;
}

// ---------- bf16 MFMA NT GEMM, 64x128 tile ----------
__global__ void __launch_bounds__(256) gemm_bf16_m64_kernel(
    const unsigned short* __restrict__ A, const unsigned short* __restrict__ B,
    const float* __restrict__ bias, void* __restrict__ Cout,
    int M, int Nreal, int K, int lda, int ldb, int ldc, int act, int outbf)
{
  __shared__ unsigned short Asm[2][64 * 32];
  __shared__ unsigned short Bsm[2][128 * 32];
  const int tid = threadIdx.x;
  const int lane = tid & 63;
  const int wv = tid >> 6;

  int flat = blockIdx.y * gridDim.x + blockIdx.x;
  int swz = xcd_swz(flat, gridDim.x * gridDim.y);
  const int bm = (swz / gridDim.x) * 64;
  const int bn = (swz % gridDim.x) * 128;

  const int g8 = (lane >> 4) << 3;
  const int lr = lane & 15;

  const int lrow = lane >> 2;
  const int kq = (lane & 3) << 3;
  const unsigned short* AgP = A + (size_t)(bm + wv * 16 + lrow) * lda + kq;
  int brow1 = bn + wv * 16 + lrow;      if (brow1 >= Nreal) brow1 = Nreal - 1;
  int brow2 = bn + 64 + wv * 16 + lrow; if (brow2 >= Nreal) brow2 = Nreal - 1;
  const unsigned short* BgP1 = B + (size_t)brow1 * ldb + kq;
  const unsigned short* BgP2 = B + (size_t)brow2 * ldb + kq;

  f4 acc[4][2];
#pragma unroll
  for (int m = 0; m < 4; ++m)
#pragma unroll
    for (int n = 0; n < 2; ++n) { acc[m][n].x = 0.f; acc[m][n].y = 0.f; acc[m][n].z = 0.f; acc[m][n].w = 0.f; }

  const int nt = K >> 5;
  gload16(AgP, &Asm[0][(wv * 16) * 32]);
  gload16(BgP1, &Bsm[0][(wv * 16) * 32]);
  gload16(BgP2, &Bsm[0][(64 + wv * 16) * 32]);
  asm volatile("s_waitcnt vmcnt(0)" ::: "memory");
  __syncthreads();

  int cur = 0;
  for (int t = 0; t < nt; ++t) {
    if (t + 1 < nt) {
      int ko = (t + 1) << 5;
      gload16(AgP + ko, &Asm[cur ^ 1][(wv * 16) * 32]);
      gload16(BgP1 + ko, &Bsm[cur ^ 1][(wv * 16) * 32]);
      gload16(BgP2 + ko, &Bsm[cur ^ 1][(64 + wv * 16) * 32]);
    }
    s8v af[4], bf[2];
#pragma unroll
    for (int m = 0; m < 4; ++m)
      af[m] = *(const s8v*)&Asm[cur][(m * 16 + lr) * 32 + g8];
#pragma unroll
    for (int n = 0; n < 2; ++n)
      bf[n] = *(const s8v*)&Bsm[cur][(wv * 32 + n * 16 + lr) * 32 + g8];
#pragma unroll
    for (int m = 0; m < 4; ++m)
#pragma unroll
      for (int n = 0; n < 2; ++n)
        acc[m][n] = __builtin_amdgcn_mfma_f32_16x16x32_bf16(af[m], bf[n], acc[m][n], 0, 0, 0);
    asm volatile("s_waitcnt vmcnt(0)" ::: "memory");
    __syncthreads();
    cur ^= 1;
  }

  const int g4 = (lane >> 4) << 2;
#pragma unroll
  for (int m = 0; m < 4; ++m) {
    int r = bm + m * 16 + g4;
#pragma unroll
    for (int n = 0; n < 2; ++n) {
      int cidx = bn + wv * 32 + n * 16 + lr;
      float bb = (cidx < Nreal) ? bias[cidx] : 0.f;
#pragma unroll
      for (int j = 0; j < 4; ++j) {
        int rr = r + j;
        float v = acc[m][n][j] + bb;
        if (act) v = gelu_f(v);
        if (cidx >= Nreal) v = 0.f;
        if (outbf) ((unsigned short*)Cout)[(size_t)rr * ldc + cidx] = f2b(v);
        else       ((float*)Cout)[(size_t)rr * ldc + cidx] = v;
      }
    }
  }
}

// ---------- split-K variant: blockIdx.z = K-chunk, writes fp32 partials ----------
__global__ void __launch_bounds__(256) gemm_bf16_splitk_kernel(
    const unsigned short* __restrict__ A, const unsigned short* __restrict__ B,
    float* __restrict__ Cpart, float* __restrict__ Calt, float* __restrict__ Calt2,
    int M, int N, int Kc, int lda, int ldb)
{
  __shared__ unsigned short Asm[2][128 * 32];
  __shared__ unsigned short Bsm[2][128 * 32];
  const int tid = threadIdx.x;
  const int lane = tid & 63;
  const int wv = tid >> 6;
  const int wr = wv >> 1, wc = wv & 1;

  int flat = blockIdx.y * gridDim.x + blockIdx.x;
  int swz = xcd_swz(flat, gridDim.x * gridDim.y);
  const int bm = (swz / gridDim.x) * 128;
  const int bn = (swz % gridDim.x) * 128;
  const int z = blockIdx.z;
  const int kbase = z * Kc;

  const int g8 = (lane >> 4) << 3;
  const int lr = lane & 15;

  const int srow = wv * 32 + (lane >> 2);
  const int kcol = (lane & 3) << 3;
  int ar0 = bm + srow;      if (ar0 >= M) ar0 = M - 1;
  int ar1 = bm + srow + 16; if (ar1 >= M) ar1 = M - 1;
  int br0 = bn + srow;      if (br0 >= N) br0 = N - 1;
  int br1 = bn + srow + 16; if (br1 >= N) br1 = N - 1;
  const unsigned short* Ag0 = A + (size_t)ar0 * lda + kbase + kcol;
  const unsigned short* Ag1 = A + (size_t)ar1 * lda + kbase + kcol;
  const unsigned short* Bg0 = B + (size_t)br0 * ldb + kbase + kcol;
  const unsigned short* Bg1 = B + (size_t)br1 * ldb + kbase + kcol;

  f4 acc[4][4];
#pragma unroll
  for (int m = 0; m < 4; ++m)
#pragma unroll
    for (int n = 0; n < 4; ++n) { acc[m][n].x = 0.f; acc[m][n].y = 0.f; acc[m][n].z = 0.f; acc[m][n].w = 0.f; }

  const int nt = Kc >> 5;
  gload16(Ag0, &Asm[0][(wv * 32) * 32]);
  gload16(Ag1, &Asm[0][(wv * 32 + 16) * 32]);
  gload16(Bg0, &Bsm[0][(wv * 32) * 32]);
  gload16(Bg1, &Bsm[0][(wv * 32 + 16) * 32]);
  asm volatile("s_waitcnt vmcnt(0)" ::: "memory");
  __syncthreads();

  int cur = 0;
  for (int t = 0; t < nt; ++t) {
    if (t + 1 < nt) {
      int ko = (t + 1) << 5;
      gload16(Ag0 + ko, &Asm[cur ^ 1][(wv * 32) * 32]);
      gload16(Ag1 + ko, &Asm[cur ^ 1][(wv * 32 + 16) * 32]);
      gload16(Bg0 + ko, &Bsm[cur ^ 1][(wv * 32) * 32]);
      gload16(Bg1 + ko, &Bsm[cur ^ 1][(wv * 32 + 16) * 32]);
    }
    s8v af[4], bf[4];
#pragma unroll
    for (int m = 0; m < 4; ++m)
      af[m] = *(const s8v*)&Asm[cur][(wr * 64 + m * 16 + lr) * 32 + g8];
#pragma unroll
    for (int n = 0; n < 4; ++n)
      bf[n] = *(const s8v*)&Bsm[cur][(wc * 64 + n * 16 + lr) * 32 + g8];
#pragma unroll
    for (int m = 0; m < 4; ++m)
#pragma unroll
      for (int n = 0; n < 4; ++n)
        acc[m][n] = __builtin_amdgcn_mfma_f32_16x16x32_bf16(af[m], bf[n], acc[m][n], 0, 0, 0);
    asm volatile("s_waitcnt vmcnt(0)" ::: "memory");
    __syncthreads();
    cur ^= 1;
  }

  float* Cz = (Calt && z == 1) ? Calt
            : ((Calt2 && z == 2) ? Calt2 : (Cpart + (size_t)z * M * N));
  const int g4 = (lane >> 4) << 2;
#pragma unroll
  for (int m = 0; m < 4; ++m) {
    int r = bm + wr * 64 + m * 16 + g4;
#pragma unroll
    for (int n = 0; n < 4; ++n) {
      int cidx = bn + wc * 64 + n * 16 + lr;
      if (cidx < N) {
#pragma unroll
        for (int j = 0; j < 4; ++j) {
          int rr = r + j;
          if (rr < M) Cz[(size_t)rr * N + cidx] = acc[m][n][j];
        }
      }
    }
  }
}

// ---------- combine split-K partials (generic, fp32 out; used by merger fc2) ----------
__global__ void __launch_bounds__(256) combine_gemm_kernel(
    const float* __restrict__ Cpart, int nz, const float* __restrict__ bias,
    const float* __restrict__ resid, float* __restrict__ out, int M, int N)
{
  int idx = blockIdx.x * 256 + threadIdx.x;
  int total = (M * N) >> 2;
  if (idx >= total) return;
  int r = idx / (N >> 2);
  int c4 = (idx % (N >> 2)) << 2;
  size_t off = (size_t)r * N + c4;
  float4 s = *(const float4*)(Cpart + off);
  for (int z = 1; z < nz; ++z) {
    float4 p = *(const float4*)(Cpart + (size_t)z * M * N + off);
    s.x += p.x; s.y += p.y; s.z += p.z; s.w += p.w;
  }
  float4 b = *(const float4*)(bias + c4);
  s.x += b.x; s.y += b.y; s.z += b.z; s.w += b.w;
  if (resid) {
    float4 rv = *(const float4*)(resid + off);
    s.x += rv.x; s.y += rv.y; s.z += rv.z; s.w += rv.w;
  }
  *(float4*)(out + off) = s;
}

// ---------- combine 2-3 split-K partials + bias + gelu -> bf16 (merger fc1) ----------
__global__ void __launch_bounds__(256) combine_gelu_kernel(
    const float* __restrict__ p0, const float* __restrict__ p1,
    const float* __restrict__ p2, const float* __restrict__ bias,
    unsigned short* __restrict__ out, int M, int N)
{
  int idx = blockIdx.x * 256 + threadIdx.x;
  int total = (M * N) >> 2;
  if (idx >= total) return;
  int r = idx / (N >> 2);
  int c4 = (idx % (N >> 2)) << 2;
  size_t off = (size_t)r * N + c4;
  float4 a = *(const float4*)(p0 + off);
  float4 b = *(const float4*)(p1 + off);
  float4 bi = *(const float4*)(bias + c4);
  float sx = a.x + b.x + bi.x, sy = a.y + b.y + bi.y;
  float sz = a.z + b.z + bi.z, sw = a.w + b.w + bi.w;
  if (p2) {
    float4 cc = *(const float4*)(p2 + off);
    sx += cc.x; sy += cc.y; sz += cc.z; sw += cc.w;
  }
  unsigned short o[4];
  o[0] = f2b(gelu_f(sx));
  o[1] = f2b(gelu_f(sy));
  o[2] = f2b(gelu_f(sz));
  o[3] = f2b(gelu_f(sw));
  *(uint2*)(out + off) = *(uint2*)o;
}

// ---------- fused split-K combine (+bias, +resid, +pos) + LayerNorm ----------
__global__ void __launch_bounds__(256) combine_ln_kernel(
    const float* __restrict__ Cpart, int nz, const float* __restrict__ bias,
    const float* __restrict__ resid, const float* __restrict__ pos_tab,
    float* __restrict__ xout, const float* __restrict__ lnw,
    const float* __restrict__ lnb, unsigned short* __restrict__ hout)
{
  __shared__ float red[8];
  const int row = blockIdx.x;
  const int tid = threadIdx.x;
  const float* pos = pos_tab ? pos_tab + (size_t)pos_id_of(row) * HDIM : nullptr;
  float v[5];
  float s1 = 0.f;
#pragma unroll
  for (int t = 0; t < 5; ++t) {
    int i = tid + t * 256;
    float s = 0.f;
    if (i < HDIM) {
      size_t off = (size_t)row * HDIM + i;
      s = Cpart[off];
      for (int z = 1; z < nz; ++z) s += Cpart[(size_t)z * ((size_t)S * HDIM) + off];
      s += bias[i];
      if (resid) s += resid[off];
      if (pos) s += pos[i];
      xout[off] = s;
    }
    v[t] = s;
    s1 += s;
  }
#pragma unroll
  for (int off = 32; off > 0; off >>= 1) s1 += __shfl_down(s1, off);
  if ((tid & 63) == 0) red[tid >> 6] = s1;
  __syncthreads();
  float mean = (red[0] + red[1] + red[2] + red[3]) * (1.f / HDIM);
  float s2 = 0.f;
#pragma unroll
  for (int t = 0; t < 5; ++t) {
    int i = tid + t * 256;
    if (i < HDIM) { float d = v[t] - mean; s2 += d * d; }
  }
#pragma unroll
  for (int off = 32; off > 0; off >>= 1) s2 += __shfl_down(s2, off);
  __syncthreads();
  if ((tid & 63) == 0) red[tid >> 6] = s2;
  __syncthreads();
  float var = (red[0] + red[1] + red[2] + red[3]) * (1.f / HDIM);
  float rstd = rsqrtf(var + 1e-6f);
#pragma unroll
  for (int t = 0; t < 5; ++t) {
    int i = tid + t * 256;
    if (i < HDIM)
      hout[(size_t)row * HDIM + i] = f2b(lnw[i] * ((v[t] - mean) * rstd) + lnb[i]);
  }
}

// ---------- RoPE tables ----------
__global__ void rope_tables_kernel(float* __restrict__ cosT, float* __restrict__ sinT)
{
  int s = blockIdx.x;
  int j = threadIdx.x;
  if (j >= 36) return;
  int pid = pos_id_of(s);
  float hp = (float)(pid / 48);
  float wp = (float)(pid % 48);
  int f = (j < 18) ? j : (j - 18);
  float inv = powf(10000.f, -(2.f * (float)f) / 36.f);
  float ang = ((j < 18) ? hp : wp) * inv;
  cosT[s * 36 + j] = cosf(ang);
  sinT[s * 36 + j] = sinf(ang);
}

// ---------- seg ids ----------
__global__ void seg_kernel(const int* __restrict__ cu, int n_cu, int* __restrict__ seg)
{
  int i = blockIdx.x * 256 + threadIdx.x;
  if (i >= S) return;
  int s = 0;
  for (int t = 0; t < n_cu; ++t) s += (cu[t] <= i) ? 1 : 0;
  seg[i] = s;
}

// ---------- RoPE apply, 2 rotation pairs per thread (bf16 in/out, fp32 math) ----------
__global__ void __launch_bounds__(256) rope_kernel(unsigned short* __restrict__ qkv,
    const float* __restrict__ cosT, const float* __restrict__ sinT)
{
  int idx = blockIdx.x * 256 + threadIdx.x;   // over S*2*NH*18
  int d2 = (idx % 18) * 2;
  int t = idx / 18;
  int hh = t % NHEAD; t /= NHEAD;
  int qk = t & 1; int s = t >> 1;
  unsigned short* base = qkv + (size_t)s * 3456 + qk * 1152 + hh * 72;
  float2 cc = *(const float2*)&cosT[s * 36 + d2];
  float2 ss = *(const float2*)&sinT[s * 36 + d2];
  unsigned int u0 = *(unsigned int*)&base[d2];
  unsigned int u1 = *(unsigned int*)&base[d2 + 36];
  float x0 = b2f((unsigned short)u0), x1 = b2f((unsigned short)(u0 >> 16));
  float y0 = b2f((unsigned short)u1), y1 = b2f((unsigned short)(u1 >> 16));
  unsigned int r0 = (unsigned int)f2b(x0 * cc.x - y0 * ss.x)
                  | ((unsigned int)f2b(x1 * cc.y - y1 * ss.y) << 16);
  unsigned int r1 = (unsigned int)f2b(y0 * cc.x + x0 * ss.x)
                  | ((unsigned int)f2b(y1 * cc.y + x1 * ss.y) << 16);
  *(unsigned int*)&base[d2] = r0;
  *(unsigned int*)&base[d2 + 36] = r1;
}

// ---------- MFMA flash attention: fused sub-blocks (round-17 config, stride 80) ----------
#define KT 64
#define ASCALE2 (0.11785113019775793f * 1.4426950408889634f)
#define DEFER_THR 11.5415603f   // 8 * log2(e)

__global__ void __launch_bounds__(256) flash_mfma_kernel(
    const unsigned short* __restrict__ qkv, unsigned short* __restrict__ opart,
    float* __restrict__ ml, const int* __restrict__ seg)
{
  __shared__ __align__(16) unsigned short Ks[64 * 80];
  __shared__ __align__(16) unsigned short Vt[80 * 80];
  __shared__ __align__(16) unsigned short Ps[8][16 * 80];   // [wv]=subA, [4+wv]=subB

  const int tid = threadIdx.x;
  const int lane = tid & 63;
  const int wv = tid >> 6;
  const int g = lane >> 4;
  const int c = lane & 15;
  const int cm = c & 7;

  int flat = (blockIdx.z * NHEAD + blockIdx.y) * (S / 128) + blockIdx.x;
  int swz = xcd_swz(flat, (S / 128) * NHEAD * NSPLIT);
  const int q0 = (swz % (S / 128)) * 128;
  const int hh = (swz / (S / 128)) % NHEAD;
  const int sidx = swz / ((S / 128) * NHEAD);
  const int kbeg = sidx * KHALF;
  const int qr = q0 + wv * 32;

  for (int i = tid; i < 320; i += 256)
    ((unsigned int*)&Vt[72 * 80])[i] = 0u;

  const bool uni = (seg[q0] == seg[q0 + 127]) && (seg[kbeg] == seg[kbeg + KHALF - 1])
                && (seg[q0] == seg[kbeg]);
  const int msgA = seg[qr + c];
  const int msgB = seg[qr + 16 + c];

  s8v qfA[3], qfB[3];
  {
    const unsigned short* qa = qkv + (size_t)(qr + c) * 3456 + hh * HD;
    const unsigned short* qb = qkv + (size_t)(qr + 16 + c) * 3456 + hh * HD;
#pragma unroll
    for (int ks = 0; ks < 3; ++ks) {
      int k = ks * 32 + g * 8;
      if (k <= 64) { qfA[ks] = *(const s8v*)(qa + k); qfB[ks] = *(const s8v*)(qb + k); }
      else {
        s8v z;
#pragma unroll
        for (int t = 0; t < 8; ++t) z[t] = 0;
        qfA[ks] = z; qfB[ks] = z;
      }
    }
  }

  float mA = -1e30f, lA = 0.f, mB = -1e30f, lB = 0.f;
  f4 accoA[5], accoB[5];
#pragma unroll
  for (int n = 0; n < 5; ++n) {
    accoA[n].x = 0.f; accoA[n].y = 0.f; accoA[n].z = 0.f; accoA[n].w = 0.f;
    accoB[n].x = 0.f; accoB[n].y = 0.f; accoB[n].z = 0.f; accoB[n].w = 0.f;
  }

  uint4 kreg[3], vreg[3];

#define STAGE_LOAD(KT0)                                                                  \
  {                                                                                      \
    _Pragma("unroll")                                                                    \
    for (int ii = 0; ii < 3; ++ii) {                                                     \
      int idx = tid + ii * 256;                                                          \
      if (idx < 576) {                                                                   \
        int rK = idx / 9, cK = idx % 9;                                                  \
        kreg[ii] = *(const uint4*)(qkv + (size_t)((KT0) + rK) * 3456 + 1152 + hh * HD + cK * 8); \
        int rV = idx & 63, cV = idx >> 6;                                                \
        vreg[ii] = *(const uint4*)(qkv + (size_t)((KT0) + rV) * 3456 + 2304 + hh * HD + cV * 8); \
      }                                                                                  \
    }                                                                                    \
  }

#define STAGE_WRITE()                                                                    \
  {                                                                                      \
    _Pragma("unroll")                                                                    \
    for (int ii = 0; ii < 3; ++ii) {                                                     \
      int idx = tid + ii * 256;                                                          \
      if (idx < 576) {                                                                   \
        int rK = idx / 9, cK = idx % 9;                                                  \
        int colx = (cK < 8) ? ((cK ^ (rK & 7)) << 3) : 64;                               \
        *(uint4*)&Ks[rK * 80 + colx] = kreg[ii];                                         \
        int rV = idx & 63, cV = idx >> 6;                                                \
        unsigned short vv[8];                                                            \
        *(uint4*)vv = vreg[ii];                                                          \
        _Pragma("unroll")                                                                \
        for (int e = 0; e < 8; ++e) {                                                    \
          int drow = cV * 8 + e;                                                         \
          Vt[drow * 80 + (rV ^ ((drow & 7) << 3))] = vv[e];                              \
        }                                                                                \
      }                                                                                  \
    }                                                                                    \
  }

// softmax + Ps write + O-rescale for one sub-block (scores in ACCS)
#define SOFTMAX_PS(ACCS, MSG, MM, LL, ACCO, PSIDX)                                       \
  {                                                                                      \
    float sc[4][4];                                                                      \
    float mx = -1e30f;                                                                   \
    if (uni) {                                                                           \
      _Pragma("unroll")                                                                  \
      for (int nk = 0; nk < 4; ++nk)                                                     \
        _Pragma("unroll")                                                                \
        for (int j = 0; j < 4; ++j) {                                                    \
          float vv = ACCS[nk][j] * ASCALE2;                                              \
          sc[nk][j] = vv; mx = fmaxf(mx, vv);                                            \
        }                                                                                \
    } else {                                                                             \
      _Pragma("unroll")                                                                  \
      for (int nk = 0; nk < 4; ++nk)                                                     \
        _Pragma("unroll")                                                                \
        for (int j = 0; j < 4; ++j) {                                                    \
          int kk = k0 + nk * 16 + g * 4 + j;                                             \
          float vv = ACCS[nk][j] * ASCALE2 + ((seg[kk] == MSG) ? 0.f : -1e9f);            \
          sc[nk][j] = vv; mx = fmaxf(mx, vv);                                            \
        }                                                                                \
    }                                                                                    \
    mx = fmaxf(mx, __shfl_xor(mx, 16));                                                  \
    mx = fmaxf(mx, __shfl_xor(mx, 32));                                                  \
    const bool allkeep = __all(mx <= MM + DEFER_THR);                                    \
    float al = 1.0f;                                                                     \
    if (!allkeep) {                                                                      \
      float mn = fmaxf(MM, mx);                                                          \
      al = exp2f(MM - mn);                                                               \
      MM = mn;                                                                           \
    }                                                                                    \
    float rsum = 0.f;                                                                    \
    float p[4][4];                                                                       \
    _Pragma("unroll")                                                                    \
    for (int nk = 0; nk < 4; ++nk)                                                       \
      _Pragma("unroll")                                                                  \
      for (int j = 0; j < 4; ++j) {                                                      \
        float pv = exp2f(sc[nk][j] - MM);                                                \
        p[nk][j] = pv; rsum += pv;                                                       \
      }                                                                                  \
    rsum += __shfl_xor(rsum, 16);                                                        \
    rsum += __shfl_xor(rsum, 32);                                                        \
    LL = LL * al + rsum;                                                                 \
    _Pragma("unroll")                                                                    \
    for (int nk = 0; nk < 4; ++nk) {                                                     \
      unsigned int w0 = (unsigned int)f2b(p[nk][0]) | ((unsigned int)f2b(p[nk][1]) << 16); \
      unsigned int w1 = (unsigned int)f2b(p[nk][2]) | ((unsigned int)f2b(p[nk][3]) << 16); \
      uint2 wv2; wv2.x = w0; wv2.y = w1;                                                 \
      *(uint2*)&Ps[PSIDX][c * 80 + ((nk * 16 + g * 4) ^ (cm << 3))] = wv2;               \
    }                                                                                    \
    if (!allkeep) {                                                                      \
      float alpha_row[4];                                                                \
      _Pragma("unroll")                                                                  \
      for (int j = 0; j < 4; ++j)                                                        \
        alpha_row[j] = __shfl(al, (lane & 48) | (g * 4 + j));                            \
      _Pragma("unroll")                                                                  \
      for (int n = 0; n < 5; ++n)                                                        \
        _Pragma("unroll")                                                                \
        for (int j = 0; j < 4; ++j) ACCO[n][j] *= alpha_row[j];                          \
    }                                                                                    \
  }

  STAGE_LOAD(kbeg);
  asm volatile("s_waitcnt vmcnt(0)" ::: "memory");
  STAGE_WRITE();
  asm volatile("s_waitcnt lgkmcnt(0)" ::: "memory");
  __builtin_amdgcn_s_barrier();
  __builtin_amdgcn_sched_barrier(0);

  for (int k0 = kbeg; k0 < kbeg + KHALF; k0 += KT) {
    const bool more = (k0 + KT < kbeg + KHALF);
    if (more) STAGE_LOAD(k0 + KT);

    // fused QK^T: each Ks read feeds both sub-blocks' MFMAs
    f4 accsA[4], accsB[4];
#pragma unroll
    for (int nk = 0; nk < 4; ++nk) {
      accsA[nk].x = 0.f; accsA[nk].y = 0.f; accsA[nk].z = 0.f; accsA[nk].w = 0.f;
      accsB[nk].x = 0.f; accsB[nk].y = 0.f; accsB[nk].z = 0.f; accsB[nk].w = 0.f;
    }
#pragma unroll
    for (int ks = 0; ks < 3; ++ks) {
      const int koff = (ks < 2) ? (((ks * 4 + g) ^ cm) << 3) : 64;
#pragma unroll
      for (int nk = 0; nk < 4; ++nk) {
        s8v bk = *(const s8v*)&Ks[(nk * 16 + c) * 80 + koff];
        accsA[nk] = __builtin_amdgcn_mfma_f32_16x16x32_bf16(bk, qfA[ks], accsA[nk], 0, 0, 0);
        accsB[nk] = __builtin_amdgcn_mfma_f32_16x16x32_bf16(bk, qfB[ks], accsB[nk], 0, 0, 0);
      }
    }

    SOFTMAX_PS(accsA, msgA, mA, lA, accoA, wv);
    SOFTMAX_PS(accsB, msgB, mB, lB, accoB, 4 + wv);

    // single same-wave Ps write->read sync for both sub-blocks
    asm volatile("s_waitcnt lgkmcnt(0)" ::: "memory");
    __builtin_amdgcn_sched_barrier(0);

    // fused PV: each Vt read feeds both sub-blocks' MFMAs
#pragma unroll
    for (int ks = 0; ks < 2; ++ks) {
      const int poff = ((ks * 4 + g) ^ cm) << 3;
      s8v paA = *(const s8v*)&Ps[wv][c * 80 + poff];
      s8v paB = *(const s8v*)&Ps[4 + wv][c * 80 + poff];
#pragma unroll
      for (int n = 0; n < 5; ++n) {
        s8v vb = *(const s8v*)&Vt[(n * 16 + c) * 80 + poff];
        accoA[n] = __builtin_amdgcn_mfma_f32_16x16x32_bf16(paA, vb, accoA[n], 0, 0, 0);
        accoB[n] = __builtin_amdgcn_mfma_f32_16x16x32_bf16(paB, vb, accoB[n], 0, 0, 0);
      }
    }

    asm volatile("s_waitcnt lgkmcnt(0)" ::: "memory");
    __builtin_amdgcn_s_barrier();
    if (more) {
      asm volatile("s_waitcnt vmcnt(0)" ::: "memory");
      STAGE_WRITE();
      asm volatile("s_waitcnt lgkmcnt(0)" ::: "memory");
    }
    __builtin_amdgcn_s_barrier();
    __builtin_amdgcn_sched_barrier(0);
  }

  unsigned short* op = opart + (size_t)(sidx * NHEAD + hh) * S * 72;
  float lrA[4], mrA[4], lrB[4], mrB[4];
#pragma unroll
  for (int j = 0; j < 4; ++j) {
    int src = (lane & 48) | (g * 4 + j);
    lrA[j] = __shfl(lA, src); mrA[j] = __shfl(mA, src);
    lrB[j] = __shfl(lB, src); mrB[j] = __shfl(mB, src);
  }
#pragma unroll
  for (int n = 0; n < 5; ++n) {
    int col = n * 16 + c;
    if (col < HD) {
#pragma unroll
      for (int j = 0; j < 4; ++j) {
        int rowA = qr + g * 4 + j;
        op[(size_t)rowA * 72 + col] = f2b(accoA[n][j]);
        op[(size_t)(rowA + 16) * 72 + col] = f2b(accoB[n][j]);
      }
    }
  }
  if (c == 0) {
#pragma unroll
    for (int j = 0; j < 4; ++j) {
      int rowA = qr + g * 4 + j;
      float2 va; va.x = mrA[j]; va.y = lrA[j];
      *(float2*)&ml[((size_t)(sidx * NHEAD + hh) * S + rowA) * 2] = va;
      float2 vb; vb.x = mrB[j]; vb.y = lrB[j];
      *(float2*)&ml[((size_t)(sidx * NHEAD + hh) * S + rowA + 16) * 2] = vb;
    }
  }
}

// ---------- combine the NSPLIT attention partials, 4 d-elems/thread (exp2 domain) ----------
__global__ void __launch_bounds__(256) attn_combine_kernel(
    const unsigned short* __restrict__ opart, const float* __restrict__ ml,
    unsigned short* __restrict__ oout)
{
  int idx = blockIdx.x * 256 + threadIdx.x;   // over NHEAD*S*18
  int d4 = (idx % 18) * 4;
  int row = (idx / 18) % S;
  int hh = idx / (18 * S);
  float mv[NSPLIT], lv[NSPLIT];
  float ms = -1e30f;
#pragma unroll
  for (int z = 0; z < NSPLIT; ++z) {
    size_t b = (size_t)(z * NHEAD + hh) * S + row;
    mv[z] = ml[b * 2]; lv[z] = ml[b * 2 + 1];
    ms = fmaxf(ms, mv[z]);
  }
  float l = 0.f;
  float o0 = 0.f, o1 = 0.f, o2 = 0.f, o3 = 0.f;
#pragma unroll
  for (int z = 0; z < NSPLIT; ++z) {
    size_t b = (size_t)(z * NHEAD + hh) * S + row;
    float a = exp2f(mv[z] - ms);
    l += a * lv[z];
    uint2 u = *(const uint2*)&opart[b * 72 + d4];
    o0 += a * b2f((unsigned short)u.x);
    o1 += a * b2f((unsigned short)(u.x >> 16));
    o2 += a * b2f((unsigned short)u.y);
    o3 += a * b2f((unsigned short)(u.y >> 16));
  }
  float rl = 1.f / l;
  unsigned int w0 = (unsigned int)f2b(o0 * rl) | ((unsigned int)f2b(o1 * rl) << 16);
  unsigned int w1 = (unsigned int)f2b(o2 * rl) | ((unsigned int)f2b(o3 * rl) << 16);
  uint2 wv2; wv2.x = w0; wv2.y = w1;
  *(uint2*)&oout[(size_t)row * HDIM + hh * 72 + d4] = wv2;
}

// ---------- launch ----------
extern "C" void kernel_launch(void* const* d_in, const int* in_sizes, int n_in,
                              void* d_out, int out_size, void* d_ws, size_t ws_size,
                              hipStream_t stream)
{
  (void)n_in; (void)out_size; (void)ws_size;
  const float* pix    = (const float*)d_in[0];
  const int*   cu     = (const int*)d_in[1];
  const int    n_cu   = in_sizes[1];
  const float* conv_w = (const float*)d_in[2];
  const float* conv_b = (const float*)d_in[3];
  const float* pos_tab= (const float*)d_in[4];
  const float* ln1_w  = (const float*)d_in[5];
  const float* ln1_b  = (const float*)d_in[6];
  const float* ln2_w  = (const float*)d_in[7];
  const float* ln2_b  = (const float*)d_in[8];
  const float* qkv_w  = (const float*)d_in[9];
  const float* qkv_b  = (const float*)d_in[10];
  const float* proj_w = (const float*)d_in[11];
  const float* proj_b = (const float*)d_in[12];
  const float* fc1_w  = (const float*)d_in[13];
  const float* fc1_b  = (const float*)d_in[14];
  const float* fc2_w  = (const float*)d_in[15];
  const float* fc2_b  = (const float*)d_in[16];
  const float* mn_w   = (const float*)d_in[17];
  const float* mn_b   = (const float*)d_in[18];
  const float* mf1_w  = (const float*)d_in[19];
  const float* mf1_b  = (const float*)d_in[20];
  const float* mf2_w  = (const float*)d_in[21];
  const float* mf2_b  = (const float*)d_in[22];
  float* out = (float*)d_out;

  float*    x      = (float*)d_ws;                                        // S*HDIM f32
  unsigned short* h_bf   = (unsigned short*)(x + (size_t)S * HDIM);       // S*HDIM bf16
  unsigned short* qkv_bf = h_bf + (size_t)S * HDIM;                       // S*3456 bf16
  unsigned short* A_bf   = qkv_bf + (size_t)S * 3456;                     // S*INTERP bf16
  unsigned short* Wbuf   = A_bf + (size_t)S * INTERP;                     // 4608*4608 bf16
  float*    cosT   = (float*)(Wbuf + (size_t)MERGED * MERGED);
  float*    sinT   = cosT + (size_t)S * 36;
  int*      seg    = (int*)(sinT + (size_t)S * 36);
  unsigned short* pix_bf = A_bf;          // alias (patch embed only)
  unsigned short* opart  = A_bf;          // alias (attention; spills 2.3MB into Wq region, dead by then)
  float*    ml     = (float*)(A_bf + (size_t)NSPLIT * NHEAD * S * 72);
  float*    part_h = (float*)h_bf;        // 21.2 MB region (h_bf+qkv_bf)
  float*    part_q = (float*)qkv_bf;      // 35.9 MB region (qkv_bf+A_bf)

  // per-layer weight sub-buffers inside Wbuf
  unsigned short* Wq = Wbuf;
  unsigned short* Wp = Wq + (size_t)3456 * HDIM;
  unsigned short* W1 = Wp + (size_t)HDIM * HDIM;
  unsigned short* W2 = W1 + (size_t)INTER * HDIM;

  auto cvt = [&](const float* src, unsigned short* dst, int N, int Ksrc, int Kdst) {
    int total = N * (Kdst >> 3);
    cvt_kernel<<<(total + 255) / 256, 256, 0, stream>>>(src, dst, N, Ksrc, Kdst);
  };
  auto gemm64 = [&](const unsigned short* A, const unsigned short* B, const float* bias,
                    void* C, int M, int N, int K, int lda, int ldb, int ldc, int act, int outbf) {
    gemm_bf16_m64_kernel<<<dim3((N + 127) / 128, M / 64), 256, 0, stream>>>(
        A, B, bias, C, M, N, K, lda, ldb, ldc, act, outbf);
  };
  auto splitk = [&](const unsigned short* A, const unsigned short* B, float* part,
                    float* alt, float* alt2, int M, int N, int K, int nz, int lda, int ldb) {
    gemm_bf16_splitk_kernel<<<dim3(N / 128, (M + 127) / 128, nz), 256, 0, stream>>>(
        A, B, part, alt, alt2, M, N, K / nz, lda, ldb);
  };
  auto comb_ln = [&](float* part, int nz, const float* bias, const float* resid,
                     const float* pos, const float* lw, const float* lb) {
    combine_ln_kernel<<<S, 256, 0, stream>>>(part, nz, bias, resid, pos, x, lw, lb, h_bf);
  };

  // patch embed: fused cvt (pix + conv_w) -> split-K(2) -> combine(+pos)+ln1
  {
    int e0 = S * (KIN >> 3);
    int e1 = e0 + HDIM * (KIN >> 3);
    cvt4_kernel<<<(e1 + 255) / 256, 256, 0, stream>>>(
        pix, pix_bf, KIN, KIN, e0,
        conv_w, Wbuf, KIN, KIN, e1,
        nullptr, nullptr, 1, 8, e1,
        nullptr, nullptr, 1, 8, e1);
  }
  splitk(pix_bf, Wbuf, part_h, nullptr, nullptr, S, HDIM, KIN, 2, KIN, KIN);
  rope_tables_kernel<<<S, 64, 0, stream>>>(cosT, sinT);
  seg_kernel<<<(S + 255) / 256, 256, 0, stream>>>(cu, n_cu, seg);
  comb_ln(part_h, 2, conv_b, nullptr, pos_tab, ln1_w, ln1_b);

  for (int layer = 0; layer < DEPTH; ++layer) {
    {
      int e0 = 3456 * (HDIM >> 3);
      int e1 = e0 + HDIM * (HDIM >> 3);
      int e2 = e1 + INTER * (HDIM >> 3);
      int e3 = e2 + HDIM * (INTERP >> 3);
      cvt4_kernel<<<(e3 + 255) / 256, 256, 0, stream>>>(
          qkv_w + (size_t)layer * 3456 * HDIM, Wq, HDIM, HDIM, e0,
          proj_w + (size_t)layer * HDIM * HDIM, Wp, HDIM, HDIM, e1,
          fc1_w + (size_t)layer * INTER * HDIM, W1, HDIM, HDIM, e2,
          fc2_w + (size_t)layer * HDIM * INTER, W2, INTER, INTERP, e3);
    }
    gemm64(h_bf, Wq, qkv_b + layer * 3456, qkv_bf, S, 3456, HDIM, HDIM, HDIM, 3456, 0, 1);
    rope_kernel<<<(S * 2 * NHEAD * 18) / 256, 256, 0, stream>>>(qkv_bf, cosT, sinT);
    flash_mfma_kernel<<<dim3(S / 128, NHEAD, NSPLIT), 256, 0, stream>>>(qkv_bf, opart, ml, seg);
    attn_combine_kernel<<<(NHEAD * S * 18) / 256, 256, 0, stream>>>(opart, ml, h_bf);
    splitk(h_bf, Wp, part_q, nullptr, nullptr, S, HDIM, HDIM, 3, HDIM, HDIM);
    comb_ln(part_q, 3, proj_b + layer * HDIM, x, nullptr,
            ln2_w + layer * HDIM, ln2_b + layer * HDIM);
    gemm64(h_bf, W1, fc1_b + layer * INTER, A_bf, S, INTER, HDIM, HDIM, HDIM, INTERP, 1, 1);
    splitk(A_bf, W2, part_h, nullptr, nullptr, S, HDIM, INTERP, 2, INTERP, INTERP);
    if (layer < DEPTH - 1)
      comb_ln(part_h, 2, fc2_b + layer * HDIM, x, nullptr,
              ln1_w + (layer + 1) * HDIM, ln1_b + (layer + 1) * HDIM);
    else
      comb_ln(part_h, 2, fc2_b + layer * HDIM, x, nullptr, mn_w, mn_b);
  }

  // merger: m_norm lives in h_bf (viewed (576, 4608)); x and qkv_bf now dead.
  cvt(mf1_w, Wbuf, MERGED, MERGED, MERGED);
  // fc1 split-K(3): A = h_bf; partials z0 -> x, z1 -> qkv_bf, z2 -> A_bf + 5.3MB
  {
    float* pz0 = x;
    float* pz1 = (float*)qkv_bf;
    float* pz2 = (float*)(A_bf + (size_t)576 * MERGED);
    splitk(h_bf, Wbuf, pz0, pz1, pz2, 576, MERGED, MERGED, 3, MERGED, MERGED);
    combine_gelu_kernel<<<((576 * MERGED / 4) + 255) / 256, 256, 0, stream>>>(
        pz0, pz1, pz2, mf1_b, A_bf, 576, MERGED);
  }
  cvt(mf2_w, Wbuf, OUTD, MERGED, MERGED);
  splitk(A_bf, Wbuf, part_h, nullptr, nullptr, 576, OUTD, MERGED, 4, MERGED, MERGED);
  combine_gemm_kernel<<<((576 * OUTD / 4) + 255) / 256, 256, 0, stream>>>(
      part_h, 4, mf2_b, nullptr, out, 576, OUTD);
}

// Round 20
// 1604.391 us; speedup vs baseline: 1.0677x; 1.0217x over previous
//
#include <hip/hip_runtime.h>
#include <hip/hip_bf16.h>
#include <math.h>

#define S 2304
#define HDIM 1152
#define NHEAD 16
#define HD 72
#define INTER 4304
#define INTERP 4352   // INTER padded to multiple of 128
#define DEPTH 4
#define MERGED 4608
#define OUTD 2048
#define KIN 1536
#define NSPLIT 4
#define KHALF (S / NSPLIT)   // 576

typedef float f4 __attribute__((ext_vector_type(4)));
typedef short s8v __attribute__((ext_vector_type(8)));

// ---------- helpers ----------
__device__ __forceinline__ int pos_id_of(int s) {
  int a = s / 96;
  int r = s % 96;
  int b = r >> 2;
  int c = (r >> 1) & 1;
  int d = r & 1;
  return a * 96 + c * 48 + b * 2 + d;
}

__device__ __forceinline__ float gelu_f(float v) {
  const float c = 0.7978845608028654f;
  float t = tanhf(c * (v + 0.044715f * v * v * v));
  return 0.5f * v * (1.f + t);
}

__device__ __forceinline__ unsigned short f2b(float f) {
  __hip_bfloat16 h = __float2bfloat16(f);
  unsigned short u;
  __builtin_memcpy(&u, &h, 2);
  return u;
}
__device__ __forceinline__ float b2f(unsigned short u) {
  return __uint_as_float(((unsigned int)u) << 16);
}

__device__ __forceinline__ void gload16(const void* g, void* l) {
  __builtin_amdgcn_global_load_lds(
      (const __attribute__((address_space(1))) void*)g,
      (__attribute__((address_space(3))) void*)l, 16, 0, 0);
}

// bijective XCD-chunk swizzle (m204 form)
__device__ __forceinline__ int xcd_swz(int flat, int nwg) {
  int q = nwg >> 3, r8 = nwg & 7;
  int xcd = flat & 7, lin = flat >> 3;
  return (xcd < r8 ? xcd * (q + 1) : r8 * (q + 1) + (xcd - r8) * q) + lin;
}

// ---------- fp32 -> bf16 convert (single region, with K padding) ----------
__global__ void __launch_bounds__(256) cvt_kernel(
    const float* __restrict__ src, unsigned short* __restrict__ dst,
    int N, int Ksrc, int Kdst)
{
  int idx = blockIdx.x * 256 + threadIdx.x;
  int kc = Kdst >> 3;
  if (idx >= N * kc) return;
  int r = idx / kc;
  int c8 = (idx % kc) << 3;
  const float* sp = src + (size_t)r * Ksrc + c8;
  unsigned short outv[8];
#pragma unroll
  for (int e = 0; e < 8; ++e)
    outv[e] = (c8 + e < Ksrc) ? f2b(sp[e]) : (unsigned short)0;
  *(uint4*)(dst + (size_t)r * Kdst + c8) = *(uint4*)outv;
}

// ---------- fused 4-region fp32 -> bf16 convert ----------
__global__ void __launch_bounds__(256) cvt4_kernel(
    const float* __restrict__ s0, unsigned short* __restrict__ d0, int Ks0, int Kd0, int e0,
    const float* __restrict__ s1, unsigned short* __restrict__ d1, int Ks1, int Kd1, int e1,
    const float* __restrict__ s2, unsigned short* __restrict__ d2, int Ks2, int Kd2, int e2,
    const float* __restrict__ s3, unsigned short* __restrict__ d3, int Ks3, int Kd3, int e3)
{
  int idx = blockIdx.x * 256 + threadIdx.x;
  const float* src; unsigned short* dst; int Ksrc, Kdst, rel;
  if (idx < e0)      { src = s0; dst = d0; Ksrc = Ks0; Kdst = Kd0; rel = idx; }
  else if (idx < e1) { src = s1; dst = d1; Ksrc = Ks1; Kdst = Kd1; rel = idx - e0; }
  else if (idx < e2) { src = s2; dst = d2; Ksrc = Ks2; Kdst = Kd2; rel = idx - e1; }
  else if (idx < e3) { src = s3; dst = d3; Ksrc = Ks3; Kdst = Kd3; rel = idx - e2; }
  else return;
  int kc = Kdst >> 3;
  int r = rel / kc;
  int c8 = (rel % kc) << 3;
  const float* sp = src + (size_t)r * Ksrc + c8;
  unsigned short outv[8];
#pragma unroll
  for (int e = 0; e < 8; ++e)
    outv[e] = (c8 + e < Ksrc) ? f2b(sp[e]) : (unsigned short)0;
  *(uint4*)(dst + (size_t)r * Kdst + c8) = *(uint4*)outv;
}

// ---------- bf16 MFMA NT GEMM, 64x128 tile ----------
__global__ void __launch_bounds__(256) gemm_bf16_m64_kernel(
    const unsigned short* __restrict__ A, const unsigned short* __restrict__ B,
    const float* __restrict__ bias, void* __restrict__ Cout,
    int M, int Nreal, int K, int lda, int ldb, int ldc, int act, int outbf)
{
  __shared__ unsigned short Asm[2][64 * 32];
  __shared__ unsigned short Bsm[2][128 * 32];
  const int tid = threadIdx.x;
  const int lane = tid & 63;
  const int wv = tid >> 6;

  int flat = blockIdx.y * gridDim.x + blockIdx.x;
  int swz = xcd_swz(flat, gridDim.x * gridDim.y);
  const int bm = (swz / gridDim.x) * 64;
  const int bn = (swz % gridDim.x) * 128;

  const int g8 = (lane >> 4) << 3;
  const int lr = lane & 15;

  const int lrow = lane >> 2;
  const int kq = (lane & 3) << 3;
  const unsigned short* AgP = A + (size_t)(bm + wv * 16 + lrow) * lda + kq;
  int brow1 = bn + wv * 16 + lrow;      if (brow1 >= Nreal) brow1 = Nreal - 1;
  int brow2 = bn + 64 + wv * 16 + lrow; if (brow2 >= Nreal) brow2 = Nreal - 1;
  const unsigned short* BgP1 = B + (size_t)brow1 * ldb + kq;
  const unsigned short* BgP2 = B + (size_t)brow2 * ldb + kq;

  f4 acc[4][2];
#pragma unroll
  for (int m = 0; m < 4; ++m)
#pragma unroll
    for (int n = 0; n < 2; ++n) { acc[m][n].x = 0.f; acc[m][n].y = 0.f; acc[m][n].z = 0.f; acc[m][n].w = 0.f; }

  const int nt = K >> 5;
  gload16(AgP, &Asm[0][(wv * 16) * 32]);
  gload16(BgP1, &Bsm[0][(wv * 16) * 32]);
  gload16(BgP2, &Bsm[0][(64 + wv * 16) * 32]);
  asm volatile("s_waitcnt vmcnt(0)" ::: "memory");
  __syncthreads();

  int cur = 0;
  for (int t = 0; t < nt; ++t) {
    if (t + 1 < nt) {
      int ko = (t + 1) << 5;
      gload16(AgP + ko, &Asm[cur ^ 1][(wv * 16) * 32]);
      gload16(BgP1 + ko, &Bsm[cur ^ 1][(wv * 16) * 32]);
      gload16(BgP2 + ko, &Bsm[cur ^ 1][(64 + wv * 16) * 32]);
    }
    s8v af[4], bf[2];
#pragma unroll
    for (int m = 0; m < 4; ++m)
      af[m] = *(const s8v*)&Asm[cur][(m * 16 + lr) * 32 + g8];
#pragma unroll
    for (int n = 0; n < 2; ++n)
      bf[n] = *(const s8v*)&Bsm[cur][(wv * 32 + n * 16 + lr) * 32 + g8];
#pragma unroll
    for (int m = 0; m < 4; ++m)
#pragma unroll
      for (int n = 0; n < 2; ++n)
        acc[m][n] = __builtin_amdgcn_mfma_f32_16x16x32_bf16(af[m], bf[n], acc[m][n], 0, 0, 0);
    asm volatile("s_waitcnt vmcnt(0)" ::: "memory");
    __syncthreads();
    cur ^= 1;
  }

  const int g4 = (lane >> 4) << 2;
#pragma unroll
  for (int m = 0; m < 4; ++m) {
    int r = bm + m * 16 + g4;
#pragma unroll
    for (int n = 0; n < 2; ++n) {
      int cidx = bn + wv * 32 + n * 16 + lr;
      float bb = (cidx < Nreal) ? bias[cidx] : 0.f;
#pragma unroll
      for (int j = 0; j < 4; ++j) {
        int rr = r + j;
        float v = acc[m][n][j] + bb;
        if (act) v = gelu_f(v);
        if (cidx >= Nreal) v = 0.f;
        if (outbf) ((unsigned short*)Cout)[(size_t)rr * ldc + cidx] = f2b(v);
        else       ((float*)Cout)[(size_t)rr * ldc + cidx] = v;
      }
    }
  }
}

// ---------- split-K variant: blockIdx.z = K-chunk, explicit partial pointers ----------
// z-th chunk covers [z*Kc, min((z+1)*Kc, Ktot)); partial written to pz[z].
__global__ void __launch_bounds__(256) gemm_bf16_splitk_kernel(
    const unsigned short* __restrict__ A, const unsigned short* __restrict__ B,
    float* __restrict__ p0, float* __restrict__ p1,
    float* __restrict__ p2, float* __restrict__ p3,
    int M, int N, int Kc, int Ktot, int lda, int ldb)
{
  __shared__ unsigned short Asm[2][128 * 32];
  __shared__ unsigned short Bsm[2][128 * 32];
  const int tid = threadIdx.x;
  const int lane = tid & 63;
  const int wv = tid >> 6;
  const int wr = wv >> 1, wc = wv & 1;

  int flat = blockIdx.y * gridDim.x + blockIdx.x;
  int swz = xcd_swz(flat, gridDim.x * gridDim.y);
  const int bm = (swz / gridDim.x) * 128;
  const int bn = (swz % gridDim.x) * 128;
  const int z = blockIdx.z;
  const int kbase = z * Kc;
  int Kthis = Ktot - kbase; if (Kthis > Kc) Kthis = Kc;

  const int g8 = (lane >> 4) << 3;
  const int lr = lane & 15;

  const int srow = wv * 32 + (lane >> 2);
  const int kcol = (lane & 3) << 3;
  int ar0 = bm + srow;      if (ar0 >= M) ar0 = M - 1;
  int ar1 = bm + srow + 16; if (ar1 >= M) ar1 = M - 1;
  int br0 = bn + srow;      if (br0 >= N) br0 = N - 1;
  int br1 = bn + srow + 16; if (br1 >= N) br1 = N - 1;
  const unsigned short* Ag0 = A + (size_t)ar0 * lda + kbase + kcol;
  const unsigned short* Ag1 = A + (size_t)ar1 * lda + kbase + kcol;
  const unsigned short* Bg0 = B + (size_t)br0 * ldb + kbase + kcol;
  const unsigned short* Bg1 = B + (size_t)br1 * ldb + kbase + kcol;

  f4 acc[4][4];
#pragma unroll
  for (int m = 0; m < 4; ++m)
#pragma unroll
    for (int n = 0; n < 4; ++n) { acc[m][n].x = 0.f; acc[m][n].y = 0.f; acc[m][n].z = 0.f; acc[m][n].w = 0.f; }

  const int nt = Kthis >> 5;
  gload16(Ag0, &Asm[0][(wv * 32) * 32]);
  gload16(Ag1, &Asm[0][(wv * 32 + 16) * 32]);
  gload16(Bg0, &Bsm[0][(wv * 32) * 32]);
  gload16(Bg1, &Bsm[0][(wv * 32 + 16) * 32]);
  asm volatile("s_waitcnt vmcnt(0)" ::: "memory");
  __syncthreads();

  int cur = 0;
  for (int t = 0; t < nt; ++t) {
    if (t + 1 < nt) {
      int ko = (t + 1) << 5;
      gload16(Ag0 + ko, &Asm[cur ^ 1][(wv * 32) * 32]);
      gload16(Ag1 + ko, &Asm[cur ^ 1][(wv * 32 + 16) * 32]);
      gload16(Bg0 + ko, &Bsm[cur ^ 1][(wv * 32) * 32]);
      gload16(Bg1 + ko, &Bsm[cur ^ 1][(wv * 32 + 16) * 32]);
    }
    s8v af[4], bf[4];
#pragma unroll
    for (int m = 0; m < 4; ++m)
      af[m] = *(const s8v*)&Asm[cur][(wr * 64 + m * 16 + lr) * 32 + g8];
#pragma unroll
    for (int n = 0; n < 4; ++n)
      bf[n] = *(const s8v*)&Bsm[cur][(wc * 64 + n * 16 + lr) * 32 + g8];
#pragma unroll
    for (int m = 0; m < 4; ++m)
#pragma unroll
      for (int n = 0; n < 4; ++n)
        acc[m][n] = __builtin_amdgcn_mfma_f32_16x16x32_bf16(af[m], bf[n], acc[m][n], 0, 0, 0);
    asm volatile("s_waitcnt vmcnt(0)" ::: "memory");
    __syncthreads();
    cur ^= 1;
  }

  float* Cz = (z == 0) ? p0 : (z == 1) ? p1 : (z == 2) ? p2 : p3;
  const int g4 = (lane >> 4) << 2;
#pragma unroll
  for (int m = 0; m < 4; ++m) {
    int r = bm + wr * 64 + m * 16 + g4;
#pragma unroll
    for (int n = 0; n < 4; ++n) {
      int cidx = bn + wc * 64 + n * 16 + lr;
      if (cidx < N) {
#pragma unroll
        for (int j = 0; j < 4; ++j) {
          int rr = r + j;
          if (rr < M) Cz[(size_t)rr * N + cidx] = acc[m][n][j];
        }
      }
    }
  }
}

// ---------- combine split-K partials (contiguous, fp32 out; used by merger fc2) ----------
__global__ void __launch_bounds__(256) combine_gemm_kernel(
    const float* __restrict__ Cpart, int nz, const float* __restrict__ bias,
    const float* __restrict__ resid, float* __restrict__ out, int M, int N)
{
  int idx = blockIdx.x * 256 + threadIdx.x;
  int total = (M * N) >> 2;
  if (idx >= total) return;
  int r = idx / (N >> 2);
  int c4 = (idx % (N >> 2)) << 2;
  size_t off = (size_t)r * N + c4;
  float4 s = *(const float4*)(Cpart + off);
  for (int z = 1; z < nz; ++z) {
    float4 p = *(const float4*)(Cpart + (size_t)z * M * N + off);
    s.x += p.x; s.y += p.y; s.z += p.z; s.w += p.w;
  }
  float4 b = *(const float4*)(bias + c4);
  s.x += b.x; s.y += b.y; s.z += b.z; s.w += b.w;
  if (resid) {
    float4 rv = *(const float4*)(resid + off);
    s.x += rv.x; s.y += rv.y; s.z += rv.z; s.w += rv.w;
  }
  *(float4*)(out + off) = s;
}

// ---------- combine 2-3 split-K partials + bias + gelu -> bf16 (merger fc1) ----------
__global__ void __launch_bounds__(256) combine_gelu_kernel(
    const float* __restrict__ p0, const float* __restrict__ p1,
    const float* __restrict__ p2, const float* __restrict__ bias,
    unsigned short* __restrict__ out, int M, int N)
{
  int idx = blockIdx.x * 256 + threadIdx.x;
  int total = (M * N) >> 2;
  if (idx >= total) return;
  int r = idx / (N >> 2);
  int c4 = (idx % (N >> 2)) << 2;
  size_t off = (size_t)r * N + c4;
  float4 a = *(const float4*)(p0 + off);
  float4 b = *(const float4*)(p1 + off);
  float4 bi = *(const float4*)(bias + c4);
  float sx = a.x + b.x + bi.x, sy = a.y + b.y + bi.y;
  float sz = a.z + b.z + bi.z, sw = a.w + b.w + bi.w;
  if (p2) {
    float4 cc = *(const float4*)(p2 + off);
    sx += cc.x; sy += cc.y; sz += cc.z; sw += cc.w;
  }
  unsigned short o[4];
  o[0] = f2b(gelu_f(sx));
  o[1] = f2b(gelu_f(sy));
  o[2] = f2b(gelu_f(sz));
  o[3] = f2b(gelu_f(sw));
  *(uint2*)(out + off) = *(uint2*)o;
}

// ---------- fused split-K combine (4 partial ptrs, +bias, +resid, +pos) + LayerNorm ----------
__global__ void __launch_bounds__(256) combine_ln_kernel(
    const float* __restrict__ p0, const float* __restrict__ p1,
    const float* __restrict__ p2, const float* __restrict__ p3,
    const float* __restrict__ bias, const float* __restrict__ resid,
    const float* __restrict__ pos_tab, float* __restrict__ xout,
    const float* __restrict__ lnw, const float* __restrict__ lnb,
    unsigned short* __restrict__ hout)
{
  __shared__ float red[8];
  const int row = blockIdx.x;
  const int tid = threadIdx.x;
  const float* pos = pos_tab ? pos_tab + (size_t)pos_id_of(row) * HDIM : nullptr;
  float v[5];
  float s1 = 0.f;
#pragma unroll
  for (int t = 0; t < 5; ++t) {
    int i = tid + t * 256;
    float s = 0.f;
    if (i < HDIM) {
      size_t off = (size_t)row * HDIM + i;
      s = p0[off];
      if (p1) s += p1[off];
      if (p2) s += p2[off];
      if (p3) s += p3[off];
      s += bias[i];
      if (resid) s += resid[off];
      if (pos) s += pos[i];
      xout[off] = s;
    }
    v[t] = s;
    s1 += s;
  }
#pragma unroll
  for (int off = 32; off > 0; off >>= 1) s1 += __shfl_down(s1, off);
  if ((tid & 63) == 0) red[tid >> 6] = s1;
  __syncthreads();
  float mean = (red[0] + red[1] + red[2] + red[3]) * (1.f / HDIM);
  float s2 = 0.f;
#pragma unroll
  for (int t = 0; t < 5; ++t) {
    int i = tid + t * 256;
    if (i < HDIM) { float d = v[t] - mean; s2 += d * d; }
  }
#pragma unroll
  for (int off = 32; off > 0; off >>= 1) s2 += __shfl_down(s2, off);
  __syncthreads();
  if ((tid & 63) == 0) red[tid >> 6] = s2;
  __syncthreads();
  float var = (red[0] + red[1] + red[2] + red[3]) * (1.f / HDIM);
  float rstd = rsqrtf(var + 1e-6f);
#pragma unroll
  for (int t = 0; t < 5; ++t) {
    int i = tid + t * 256;
    if (i < HDIM)
      hout[(size_t)row * HDIM + i] = f2b(lnw[i] * ((v[t] - mean) * rstd) + lnb[i]);
  }
}

// ---------- RoPE tables ----------
__global__ void rope_tables_kernel(float* __restrict__ cosT, float* __restrict__ sinT)
{
  int s = blockIdx.x;
  int j = threadIdx.x;
  if (j >= 36) return;
  int pid = pos_id_of(s);
  float hp = (float)(pid / 48);
  float wp = (float)(pid % 48);
  int f = (j < 18) ? j : (j - 18);
  float inv = powf(10000.f, -(2.f * (float)f) / 36.f);
  float ang = ((j < 18) ? hp : wp) * inv;
  cosT[s * 36 + j] = cosf(ang);
  sinT[s * 36 + j] = sinf(ang);
}

// ---------- seg ids ----------
__global__ void seg_kernel(const int* __restrict__ cu, int n_cu, int* __restrict__ seg)
{
  int i = blockIdx.x * 256 + threadIdx.x;
  if (i >= S) return;
  int s = 0;
  for (int t = 0; t < n_cu; ++t) s += (cu[t] <= i) ? 1 : 0;
  seg[i] = s;
}

// ---------- RoPE apply, 2 rotation pairs per thread (bf16 in/out, fp32 math) ----------
__global__ void __launch_bounds__(256) rope_kernel(unsigned short* __restrict__ qkv,
    const float* __restrict__ cosT, const float* __restrict__ sinT)
{
  int idx = blockIdx.x * 256 + threadIdx.x;   // over S*2*NH*18
  int d2 = (idx % 18) * 2;
  int t = idx / 18;
  int hh = t % NHEAD; t /= NHEAD;
  int qk = t & 1; int s = t >> 1;
  unsigned short* base = qkv + (size_t)s * 3456 + qk * 1152 + hh * 72;
  float2 cc = *(const float2*)&cosT[s * 36 + d2];
  float2 ss = *(const float2*)&sinT[s * 36 + d2];
  unsigned int u0 = *(unsigned int*)&base[d2];
  unsigned int u1 = *(unsigned int*)&base[d2 + 36];
  float x0 = b2f((unsigned short)u0), x1 = b2f((unsigned short)(u0 >> 16));
  float y0 = b2f((unsigned short)u1), y1 = b2f((unsigned short)(u1 >> 16));
  unsigned int r0 = (unsigned int)f2b(x0 * cc.x - y0 * ss.x)
                  | ((unsigned int)f2b(x1 * cc.y - y1 * ss.y) << 16);
  unsigned int r1 = (unsigned int)f2b(y0 * cc.x + x0 * ss.x)
                  | ((unsigned int)f2b(y1 * cc.y + x1 * ss.y) << 16);
  *(unsigned int*)&base[d2] = r0;
  *(unsigned int*)&base[d2 + 36] = r1;
}

// ---------- MFMA flash attention: fused sub-blocks (round-17 config, stride 80) ----------
#define KT 64
#define ASCALE2 (0.11785113019775793f * 1.4426950408889634f)
#define DEFER_THR 11.5415603f   // 8 * log2(e)

__global__ void __launch_bounds__(256) flash_mfma_kernel(
    const unsigned short* __restrict__ qkv, unsigned short* __restrict__ opart,
    float* __restrict__ ml, const int* __restrict__ seg)
{
  __shared__ __align__(16) unsigned short Ks[64 * 80];
  __shared__ __align__(16) unsigned short Vt[80 * 80];
  __shared__ __align__(16) unsigned short Ps[8][16 * 80];   // [wv]=subA, [4+wv]=subB

  const int tid = threadIdx.x;
  const int lane = tid & 63;
  const int wv = tid >> 6;
  const int g = lane >> 4;
  const int c = lane & 15;
  const int cm = c & 7;

  int flat = (blockIdx.z * NHEAD + blockIdx.y) * (S / 128) + blockIdx.x;
  int swz = xcd_swz(flat, (S / 128) * NHEAD * NSPLIT);
  const int q0 = (swz % (S / 128)) * 128;
  const int hh = (swz / (S / 128)) % NHEAD;
  const int sidx = swz / ((S / 128) * NHEAD);
  const int kbeg = sidx * KHALF;
  const int qr = q0 + wv * 32;

  for (int i = tid; i < 320; i += 256)
    ((unsigned int*)&Vt[72 * 80])[i] = 0u;

  const bool uni = (seg[q0] == seg[q0 + 127]) && (seg[kbeg] == seg[kbeg + KHALF - 1])
                && (seg[q0] == seg[kbeg]);
  const int msgA = seg[qr + c];
  const int msgB = seg[qr + 16 + c];

  s8v qfA[3], qfB[3];
  {
    const unsigned short* qa = qkv + (size_t)(qr + c) * 3456 + hh * HD;
    const unsigned short* qb = qkv + (size_t)(qr + 16 + c) * 3456 + hh * HD;
#pragma unroll
    for (int ks = 0; ks < 3; ++ks) {
      int k = ks * 32 + g * 8;
      if (k <= 64) { qfA[ks] = *(const s8v*)(qa + k); qfB[ks] = *(const s8v*)(qb + k); }
      else {
        s8v z;
#pragma unroll
        for (int t = 0; t < 8; ++t) z[t] = 0;
        qfA[ks] = z; qfB[ks] = z;
      }
    }
  }

  float mA = -1e30f, lA = 0.f, mB = -1e30f, lB = 0.f;
  f4 accoA[5], accoB[5];
#pragma unroll
  for (int n = 0; n < 5; ++n) {
    accoA[n].x = 0.f; accoA[n].y = 0.f; accoA[n].z = 0.f; accoA[n].w = 0.f;
    accoB[n].x = 0.f; accoB[n].y = 0.f; accoB[n].z = 0.f; accoB[n].w = 0.f;
  }

  uint4 kreg[3], vreg[3];

#define STAGE_LOAD(KT0)                                                                  \
  {                                                                                      \
    _Pragma("unroll")                                                                    \
    for (int ii = 0; ii < 3; ++ii) {                                                     \
      int idx = tid + ii * 256;                                                          \
      if (idx < 576) {                                                                   \
        int rK = idx / 9, cK = idx % 9;                                                  \
        kreg[ii] = *(const uint4*)(qkv + (size_t)((KT0) + rK) * 3456 + 1152 + hh * HD + cK * 8); \
        int rV = idx & 63, cV = idx >> 6;                                                \
        vreg[ii] = *(const uint4*)(qkv + (size_t)((KT0) + rV) * 3456 + 2304 + hh * HD + cV * 8); \
      }                                                                                  \
    }                                                                                    \
  }

#define STAGE_WRITE()                                                                    \
  {                                                                                      \
    _Pragma("unroll")                                                                    \
    for (int ii = 0; ii < 3; ++ii) {                                                     \
      int idx = tid + ii * 256;                                                          \
      if (idx < 576) {                                                                   \
        int rK = idx / 9, cK = idx % 9;                                                  \
        int colx = (cK < 8) ? ((cK ^ (rK & 7)) << 3) : 64;                               \
        *(uint4*)&Ks[rK * 80 + colx] = kreg[ii];                                         \
        int rV = idx & 63, cV = idx >> 6;                                                \
        unsigned short vv[8];                                                            \
        *(uint4*)vv = vreg[ii];                                                          \
        _Pragma("unroll")                                                                \
        for (int e = 0; e < 8; ++e) {                                                    \
          int drow = cV * 8 + e;                                                         \
          Vt[drow * 80 + (rV ^ ((drow & 7) << 3))] = vv[e];                              \
        }                                                                                \
      }                                                                                  \
    }                                                                                    \
  }

// softmax + Ps write + O-rescale for one sub-block (scores in ACCS)
#define SOFTMAX_PS(ACCS, MSG, MM, LL, ACCO, PSIDX)                                       \
  {                                                                                      \
    float sc[4][4];                                                                      \
    float mx = -1e30f;                                                                   \
    if (uni) {                                                                           \
      _Pragma("unroll")                                                                  \
      for (int nk = 0; nk < 4; ++nk)                                                     \
        _Pragma("unroll")                                                                \
        for (int j = 0; j < 4; ++j) {                                                    \
          float vv = ACCS[nk][j] * ASCALE2;                                              \
          sc[nk][j] = vv; mx = fmaxf(mx, vv);                                            \
        }                                                                                \
    } else {                                                                             \
      _Pragma("unroll")                                                                  \
      for (int nk = 0; nk < 4; ++nk)                                                     \
        _Pragma("unroll")                                                                \
        for (int j = 0; j < 4; ++j) {                                                    \
          int kk = k0 + nk * 16 + g * 4 + j;                                             \
          float vv = ACCS[nk][j] * ASCALE2 + ((seg[kk] == MSG) ? 0.f : -1e9f);            \
          sc[nk][j] = vv; mx = fmaxf(mx, vv);                                            \
        }                                                                                \
    }                                                                                    \
    mx = fmaxf(mx, __shfl_xor(mx, 16));                                                  \
    mx = fmaxf(mx, __shfl_xor(mx, 32));                                                  \
    const bool allkeep = __all(mx <= MM + DEFER_THR);                                    \
    float al = 1.0f;                                                                     \
    if (!allkeep) {                                                                      \
      float mn = fmaxf(MM, mx);                                                          \
      al = exp2f(MM - mn);                                                               \
      MM = mn;                                                                           \
    }                                                                                    \
    float rsum = 0.f;                                                                    \
    float p[4][4];                                                                       \
    _Pragma("unroll")                                                                    \
    for (int nk = 0; nk < 4; ++nk)                                                       \
      _Pragma("unroll")                                                                  \
      for (int j = 0; j < 4; ++j) {                                                      \
        float pv = exp2f(sc[nk][j] - MM);                                                \
        p[nk][j] = pv; rsum += pv;                                                       \
      }                                                                                  \
    rsum += __shfl_xor(rsum, 16);                                                        \
    rsum += __shfl_xor(rsum, 32);                                                        \
    LL = LL * al + rsum;                                                                 \
    _Pragma("unroll")                                                                    \
    for (int nk = 0; nk < 4; ++nk) {                                                     \
      unsigned int w0 = (unsigned int)f2b(p[nk][0]) | ((unsigned int)f2b(p[nk][1]) << 16); \
      unsigned int w1 = (unsigned int)f2b(p[nk][2]) | ((unsigned int)f2b(p[nk][3]) << 16); \
      uint2 wv2; wv2.x = w0; wv2.y = w1;                                                 \
      *(uint2*)&Ps[PSIDX][c * 80 + ((nk * 16 + g * 4) ^ (cm << 3))] = wv2;               \
    }                                                                                    \
    if (!allkeep) {                                                                      \
      float alpha_row[4];                                                                \
      _Pragma("unroll")                                                                  \
      for (int j = 0; j < 4; ++j)                                                        \
        alpha_row[j] = __shfl(al, (lane & 48) | (g * 4 + j));                            \
      _Pragma("unroll")                                                                  \
      for (int n = 0; n < 5; ++n)                                                        \
        _Pragma("unroll")                                                                \
        for (int j = 0; j < 4; ++j) ACCO[n][j] *= alpha_row[j];                          \
    }                                                                                    \
  }

  STAGE_LOAD(kbeg);
  asm volatile("s_waitcnt vmcnt(0)" ::: "memory");
  STAGE_WRITE();
  asm volatile("s_waitcnt lgkmcnt(0)" ::: "memory");
  __builtin_amdgcn_s_barrier();
  __builtin_amdgcn_sched_barrier(0);

  for (int k0 = kbeg; k0 < kbeg + KHALF; k0 += KT) {
    const bool more = (k0 + KT < kbeg + KHALF);
    if (more) STAGE_LOAD(k0 + KT);

    // fused QK^T: each Ks read feeds both sub-blocks' MFMAs
    f4 accsA[4], accsB[4];
#pragma unroll
    for (int nk = 0; nk < 4; ++nk) {
      accsA[nk].x = 0.f; accsA[nk].y = 0.f; accsA[nk].z = 0.f; accsA[nk].w = 0.f;
      accsB[nk].x = 0.f; accsB[nk].y = 0.f; accsB[nk].z = 0.f; accsB[nk].w = 0.f;
    }
#pragma unroll
    for (int ks = 0; ks < 3; ++ks) {
      const int koff = (ks < 2) ? (((ks * 4 + g) ^ cm) << 3) : 64;
#pragma unroll
      for (int nk = 0; nk < 4; ++nk) {
        s8v bk = *(const s8v*)&Ks[(nk * 16 + c) * 80 + koff];
        accsA[nk] = __builtin_amdgcn_mfma_f32_16x16x32_bf16(bk, qfA[ks], accsA[nk], 0, 0, 0);
        accsB[nk] = __builtin_amdgcn_mfma_f32_16x16x32_bf16(bk, qfB[ks], accsB[nk], 0, 0, 0);
      }
    }

    SOFTMAX_PS(accsA, msgA, mA, lA, accoA, wv);
    SOFTMAX_PS(accsB, msgB, mB, lB, accoB, 4 + wv);

    // single same-wave Ps write->read sync for both sub-blocks
    asm volatile("s_waitcnt lgkmcnt(0)" ::: "memory");
    __builtin_amdgcn_sched_barrier(0);

    // fused PV: each Vt read feeds both sub-blocks' MFMAs
#pragma unroll
    for (int ks = 0; ks < 2; ++ks) {
      const int poff = ((ks * 4 + g) ^ cm) << 3;
      s8v paA = *(const s8v*)&Ps[wv][c * 80 + poff];
      s8v paB = *(const s8v*)&Ps[4 + wv][c * 80 + poff];
#pragma unroll
      for (int n = 0; n < 5; ++n) {
        s8v vb = *(const s8v*)&Vt[(n * 16 + c) * 80 + poff];
        accoA[n] = __builtin_amdgcn_mfma_f32_16x16x32_bf16(paA, vb, accoA[n], 0, 0, 0);
        accoB[n] = __builtin_amdgcn_mfma_f32_16x16x32_bf16(paB, vb, accoB[n], 0, 0, 0);
      }
    }

    asm volatile("s_waitcnt lgkmcnt(0)" ::: "memory");
    __builtin_amdgcn_s_barrier();
    if (more) {
      asm volatile("s_waitcnt vmcnt(0)" ::: "memory");
      STAGE_WRITE();
      asm volatile("s_waitcnt lgkmcnt(0)" ::: "memory");
    }
    __builtin_amdgcn_s_barrier();
    __builtin_amdgcn_sched_barrier(0);
  }

  unsigned short* op = opart + (size_t)(sidx * NHEAD + hh) * S * 72;
  float lrA[4], mrA[4], lrB[4], mrB[4];
#pragma unroll
  for (int j = 0; j < 4; ++j) {
    int src = (lane & 48) | (g * 4 + j);
    lrA[j] = __shfl(lA, src); mrA[j] = __shfl(mA, src);
    lrB[j] = __shfl(lB, src); mrB[j] = __shfl(mB, src);
  }
#pragma unroll
  for (int n = 0; n < 5; ++n) {
    int col = n * 16 + c;
    if (col < HD) {
#pragma unroll
      for (int j = 0; j < 4; ++j) {
        int rowA = qr + g * 4 + j;
        op[(size_t)rowA * 72 + col] = f2b(accoA[n][j]);
        op[(size_t)(rowA + 16) * 72 + col] = f2b(accoB[n][j]);
      }
    }
  }
  if (c == 0) {
#pragma unroll
    for (int j = 0; j < 4; ++j) {
      int rowA = qr + g * 4 + j;
      float2 va; va.x = mrA[j]; va.y = lrA[j];
      *(float2*)&ml[((size_t)(sidx * NHEAD + hh) * S + rowA) * 2] = va;
      float2 vb; vb.x = mrB[j]; vb.y = lrB[j];
      *(float2*)&ml[((size_t)(sidx * NHEAD + hh) * S + rowA + 16) * 2] = vb;
    }
  }
}

// ---------- combine the NSPLIT attention partials, 4 d-elems/thread (exp2 domain) ----------
__global__ void __launch_bounds__(256) attn_combine_kernel(
    const unsigned short* __restrict__ opart, const float* __restrict__ ml,
    unsigned short* __restrict__ oout)
{
  int idx = blockIdx.x * 256 + threadIdx.x;   // over NHEAD*S*18
  int d4 = (idx % 18) * 4;
  int row = (idx / 18) % S;
  int hh = idx / (18 * S);
  float mv[NSPLIT], lv[NSPLIT];
  float ms = -1e30f;
#pragma unroll
  for (int z = 0; z < NSPLIT; ++z) {
    size_t b = (size_t)(z * NHEAD + hh) * S + row;
    mv[z] = ml[b * 2]; lv[z] = ml[b * 2 + 1];
    ms = fmaxf(ms, mv[z]);
  }
  float l = 0.f;
  float o0 = 0.f, o1 = 0.f, o2 = 0.f, o3 = 0.f;
#pragma unroll
  for (int z = 0; z < NSPLIT; ++z) {
    size_t b = (size_t)(z * NHEAD + hh) * S + row;
    float a = exp2f(mv[z] - ms);
    l += a * lv[z];
    uint2 u = *(const uint2*)&opart[b * 72 + d4];
    o0 += a * b2f((unsigned short)u.x);
    o1 += a * b2f((unsigned short)(u.x >> 16));
    o2 += a * b2f((unsigned short)u.y);
    o3 += a * b2f((unsigned short)(u.y >> 16));
  }
  float rl = 1.f / l;
  unsigned int w0 = (unsigned int)f2b(o0 * rl) | ((unsigned int)f2b(o1 * rl) << 16);
  unsigned int w1 = (unsigned int)f2b(o2 * rl) | ((unsigned int)f2b(o3 * rl) << 16);
  uint2 wv2; wv2.x = w0; wv2.y = w1;
  *(uint2*)&oout[(size_t)row * HDIM + hh * 72 + d4] = wv2;
}

// ---------- launch ----------
extern "C" void kernel_launch(void* const* d_in, const int* in_sizes, int n_in,
                              void* d_out, int out_size, void* d_ws, size_t ws_size,
                              hipStream_t stream)
{
  (void)n_in; (void)out_size; (void)ws_size;
  const float* pix    = (const float*)d_in[0];
  const int*   cu     = (const int*)d_in[1];
  const int    n_cu   = in_sizes[1];
  const float* conv_w = (const float*)d_in[2];
  const float* conv_b = (const float*)d_in[3];
  const float* pos_tab= (const float*)d_in[4];
  const float* ln1_w  = (const float*)d_in[5];
  const float* ln1_b  = (const float*)d_in[6];
  const float* ln2_w  = (const float*)d_in[7];
  const float* ln2_b  = (const float*)d_in[8];
  const float* qkv_w  = (const float*)d_in[9];
  const float* qkv_b  = (const float*)d_in[10];
  const float* proj_w = (const float*)d_in[11];
  const float* proj_b = (const float*)d_in[12];
  const float* fc1_w  = (const float*)d_in[13];
  const float* fc1_b  = (const float*)d_in[14];
  const float* fc2_w  = (const float*)d_in[15];
  const float* fc2_b  = (const float*)d_in[16];
  const float* mn_w   = (const float*)d_in[17];
  const float* mn_b   = (const float*)d_in[18];
  const float* mf1_w  = (const float*)d_in[19];
  const float* mf1_b  = (const float*)d_in[20];
  const float* mf2_w  = (const float*)d_in[21];
  const float* mf2_b  = (const float*)d_in[22];
  float* out = (float*)d_out;

  float*    x      = (float*)d_ws;                                        // S*HDIM f32
  unsigned short* h_bf   = (unsigned short*)(x + (size_t)S * HDIM);       // S*HDIM bf16
  unsigned short* qkv_bf = h_bf + (size_t)S * HDIM;                       // S*3456 bf16
  unsigned short* A_bf   = qkv_bf + (size_t)S * 3456;                     // S*INTERP bf16
  unsigned short* Wbuf   = A_bf + (size_t)S * INTERP;                     // 4608*4608 bf16
  float*    cosT   = (float*)(Wbuf + (size_t)MERGED * MERGED);
  float*    sinT   = cosT + (size_t)S * 36;
  int*      seg    = (int*)(sinT + (size_t)S * 36);
  unsigned short* pix_bf = A_bf;          // alias (patch embed only)
  unsigned short* opart  = A_bf;          // alias (attention; spills 2.3MB into Wq region, dead by then)
  float*    ml     = (float*)(A_bf + (size_t)NSPLIT * NHEAD * S * 72);
  float*    part_h = (float*)h_bf;        // 21.2 MB region (h_bf+qkv_bf) = exactly 2 S*HDIM partials
  float*    part_q = (float*)qkv_bf;      // 35.9 MB region (qkv_bf+A_bf) = 3 S*HDIM partials

  // per-layer weight sub-buffers inside Wbuf
  unsigned short* Wq = Wbuf;
  unsigned short* Wp = Wq + (size_t)3456 * HDIM;
  unsigned short* W1 = Wp + (size_t)HDIM * HDIM;
  unsigned short* W2 = W1 + (size_t)INTER * HDIM;
  const size_t SH = (size_t)S * HDIM;

  auto cvt = [&](const float* src, unsigned short* dst, int N, int Ksrc, int Kdst) {
    int total = N * (Kdst >> 3);
    cvt_kernel<<<(total + 255) / 256, 256, 0, stream>>>(src, dst, N, Ksrc, Kdst);
  };
  auto gemm64 = [&](const unsigned short* A, const unsigned short* B, const float* bias,
                    void* C, int M, int N, int K, int lda, int ldb, int ldc, int act, int outbf) {
    gemm_bf16_m64_kernel<<<dim3((N + 127) / 128, M / 64), 256, 0, stream>>>(
        A, B, bias, C, M, N, K, lda, ldb, ldc, act, outbf);
  };
  auto splitk = [&](const unsigned short* A, const unsigned short* B,
                    float* p0, float* p1, float* p2, float* p3,
                    int M, int N, int K, int nz, int lda, int ldb) {
    int Kc = (K + nz - 1) / nz;
    Kc = (Kc + 31) & ~31;                 // round chunk to multiple of 32
    gemm_bf16_splitk_kernel<<<dim3(N / 128, (M + 127) / 128, nz), 256, 0, stream>>>(
        A, B, p0, p1, p2, p3, M, N, Kc, K, lda, ldb);
  };
  auto comb_ln = [&](float* p0, float* p1, float* p2, float* p3,
                     const float* bias, const float* resid,
                     const float* pos, const float* lw, const float* lb) {
    combine_ln_kernel<<<S, 256, 0, stream>>>(p0, p1, p2, p3, bias, resid, pos, x, lw, lb, h_bf);
  };

  // patch embed: fused cvt (pix + conv_w) -> split-K(3) -> combine(+pos)+ln1
  // partials: z0,z1 -> part_h span; z2 -> x (dead; comb_ln reads p2[off] before writing xout[off])
  {
    int e0 = S * (KIN >> 3);
    int e1 = e0 + HDIM * (KIN >> 3);
    cvt4_kernel<<<(e1 + 255) / 256, 256, 0, stream>>>(
        pix, pix_bf, KIN, KIN, e0,
        conv_w, Wbuf, KIN, KIN, e1,
        nullptr, nullptr, 1, 8, e1,
        nullptr, nullptr, 1, 8, e1);
  }
  splitk(pix_bf, Wbuf, part_h, part_h + SH, x, nullptr, S, HDIM, KIN, 3, KIN, KIN);
  rope_tables_kernel<<<S, 64, 0, stream>>>(cosT, sinT);
  seg_kernel<<<(S + 255) / 256, 256, 0, stream>>>(cu, n_cu, seg);
  comb_ln(part_h, part_h + SH, x, nullptr, conv_b, nullptr, pos_tab, ln1_w, ln1_b);

  for (int layer = 0; layer < DEPTH; ++layer) {
    {
      int e0 = 3456 * (HDIM >> 3);
      int e1 = e0 + HDIM * (HDIM >> 3);
      int e2 = e1 + INTER * (HDIM >> 3);
      int e3 = e2 + HDIM * (INTERP >> 3);
      cvt4_kernel<<<(e3 + 255) / 256, 256, 0, stream>>>(
          qkv_w + (size_t)layer * 3456 * HDIM, Wq, HDIM, HDIM, e0,
          proj_w + (size_t)layer * HDIM * HDIM, Wp, HDIM, HDIM, e1,
          fc1_w + (size_t)layer * INTER * HDIM, W1, HDIM, HDIM, e2,
          fc2_w + (size_t)layer * HDIM * INTER, W2, INTER, INTERP, e3);
    }
    gemm64(h_bf, Wq, qkv_b + layer * 3456, qkv_bf, S, 3456, HDIM, HDIM, HDIM, 3456, 0, 1);
    rope_kernel<<<(S * 2 * NHEAD * 18) / 256, 256, 0, stream>>>(qkv_bf, cosT, sinT);
    flash_mfma_kernel<<<dim3(S / 128, NHEAD, NSPLIT), 256, 0, stream>>>(qkv_bf, opart, ml, seg);
    attn_combine_kernel<<<(NHEAD * S * 18) / 256, 256, 0, stream>>>(opart, ml, h_bf);
    // proj split-K(3): contiguous partials in part_q (qkv_bf+A_bf, both dead)
    splitk(h_bf, Wp, part_q, part_q + SH, part_q + 2 * SH, nullptr, S, HDIM, HDIM, 3, HDIM, HDIM);
    comb_ln(part_q, part_q + SH, part_q + 2 * SH, nullptr,
            proj_b + layer * HDIM, x, nullptr, ln2_w + layer * HDIM, ln2_b + layer * HDIM);
    gemm64(h_bf, W1, fc1_b + layer * INTER, A_bf, S, INTER, HDIM, HDIM, HDIM, INTERP, 1, 1);
    // fc2 split-K(3): z0,z1 -> part_h; z2 -> Wq+Wp span (exactly S*HDIM floats, both consumed)
    splitk(A_bf, W2, part_h, part_h + SH, (float*)Wbuf, nullptr, S, HDIM, INTERP, 3, INTERP, INTERP);
    if (layer < DEPTH - 1)
      comb_ln(part_h, part_h + SH, (float*)Wbuf, nullptr, fc2_b + layer * HDIM, x, nullptr,
              ln1_w + (layer + 1) * HDIM, ln1_b + (layer + 1) * HDIM);
    else
      comb_ln(part_h, part_h + SH, (float*)Wbuf, nullptr, fc2_b + layer * HDIM, x, nullptr,
              mn_w, mn_b);
  }

  // merger: m_norm lives in h_bf (viewed (576, 4608)); x and qkv_bf now dead.
  cvt(mf1_w, Wbuf, MERGED, MERGED, MERGED);
  // fc1 split-K(3): partials z0 -> x, z1 -> qkv_bf, z2 -> A_bf + 576*MERGED (after output region)
  {
    float* pz0 = x;
    float* pz1 = (float*)qkv_bf;
    float* pz2 = (float*)(A_bf + (size_t)576 * MERGED);
    splitk(h_bf, Wbuf, pz0, pz1, pz2, nullptr, 576, MERGED, MERGED, 3, MERGED, MERGED);
    combine_gelu_kernel<<<((576 * MERGED / 4) + 255) / 256, 256, 0, stream>>>(
        pz0, pz1, pz2, mf1_b, A_bf, 576, MERGED);
  }
  cvt(mf2_w, Wbuf, OUTD, MERGED, MERGED);
  // merger fc2 split-K(4): contiguous partials in part_h (4 x 4.7MB <= 21.2MB; h_bf dead)
  {
    size_t MN = (size_t)576 * OUTD;
    splitk(A_bf, Wbuf, part_h, part_h + MN, part_h + 2 * MN, part_h + 3 * MN,
           576, OUTD, MERGED, 4, MERGED, MERGED);
    combine_gemm_kernel<<<((576 * OUTD / 4) + 255) / 256, 256, 0, stream>>>(
        part_h, 4, mf2_b, nullptr, out, 576, OUTD);
  }
}